// Round 2
// baseline (1722.147 us; speedup 1.0000x reference)
//
#include <hip/hip_runtime.h>

#define NN 100000
#define NE 1600000
#define KD 128
#define EPSF 1e-5f

// ---------------------------------------------------------------- init ----
__global__ void zero_init_kernel(int* __restrict__ cnt, float* __restrict__ bnacc) {
    int i = blockIdx.x * blockDim.x + threadIdx.x;
    if (i < NN) cnt[i] = 0;
    if (i < 512) bnacc[i] = 0.0f;
}

__global__ void hist_kernel(const int* __restrict__ dst, int* __restrict__ cnt) {
    int e = blockIdx.x * blockDim.x + threadIdx.x;
    if (e < NE) atomicAdd(&cnt[dst[e]], 1);
}

// single block, 1024 threads: exclusive scan of counts -> row_start, cursor, deg_inv
__global__ void scan_kernel(int* __restrict__ cnt_cursor, int* __restrict__ row_start,
                            float* __restrict__ deg_inv) {
    __shared__ int sdata[1024];
    const int t = threadIdx.x;
    const int CH = (NN + 1023) / 1024;           // 98
    const int begin = t * CH;
    const int end = min(begin + CH, NN);
    int s = 0;
    for (int i = begin; i < end; i++) s += cnt_cursor[i];
    sdata[t] = s;
    __syncthreads();
    for (int off = 1; off < 1024; off <<= 1) {
        int v = (t >= off) ? sdata[t - off] : 0;
        __syncthreads();
        sdata[t] += v;
        __syncthreads();
    }
    int prefix = (t == 0) ? 0 : sdata[t - 1];
    for (int i = begin; i < end; i++) {
        int c = cnt_cursor[i];                   // read BEFORE overwrite
        row_start[i] = prefix;
        cnt_cursor[i] = prefix;                  // becomes scatter cursor
        deg_inv[i] = 1.0f / (float)(c > 1 ? c : 1);
        prefix += c;
    }
    if (t == 0) row_start[NN] = NE;
}

__global__ void scatter_kernel(const int* __restrict__ src, const int* __restrict__ dst,
                               int* __restrict__ cursor, int* __restrict__ sorted_src) {
    int e = blockIdx.x * blockDim.x + threadIdx.x;
    if (e < NE) {
        int p = atomicAdd(&cursor[dst[e]], 1);
        sorted_src[p] = src[e];
    }
}

// ------------------------------------------------------------ aggregate ----
// mean over in-neighbors. 8 nodes per 256-thread block; 32 lanes x float4 = 128 dims.
__global__ void aggregate_kernel(const float* __restrict__ X, const int* __restrict__ row_start,
                                 const int* __restrict__ sorted_src,
                                 const float* __restrict__ deg_inv, float* __restrict__ out) {
    int node = blockIdx.x * 8 + (threadIdx.x >> 5);
    int lane = threadIdx.x & 31;
    if (node >= NN) return;
    int e0 = row_start[node];
    int e1 = row_start[node + 1];
    float4 acc = {0.0f, 0.0f, 0.0f, 0.0f};
    for (int e = e0; e < e1; e++) {
        int sn = sorted_src[e];
        float4 v = *(const float4*)&X[(size_t)sn * KD + lane * 4];
        acc.x += v.x; acc.y += v.y; acc.z += v.z; acc.w += v.w;
    }
    float di = deg_inv[node];
    acc.x *= di; acc.y *= di; acc.z *= di; acc.w *= di;
    *(float4*)&out[(size_t)node * KD + lane * 4] = acc;
}

// ----------------------------------------------------------------- GEMM ----
// C[n x NOUT] = act( A1 @ W1^T (+ A2 @ W2^T) + bias ), K=128 each.
// W is [NOUT x 128] row-major (PyTorch layout). TM=128 rows/block, 256 thr,
// 8x(NOUT/16) register tile, A staged K-major in LDS -> b128 fragment reads.
template <int NOUT, bool RELU, bool DUAL>
__global__ __launch_bounds__(256) void gemm_kernel(
    const float* __restrict__ A1, const float* __restrict__ W1,
    const float* __restrict__ A2, const float* __restrict__ W2,
    const float* __restrict__ bias, float* __restrict__ C) {
    constexpr int TM = 128, BK = 32;
    constexpr int CPT = NOUT / 16;               // 8 (NOUT=128) or 4 (NOUT=64)
    __shared__ float As1[BK][TM];
    __shared__ float Ws1[BK][NOUT];
    __shared__ float As2[DUAL ? BK : 1][DUAL ? TM : 1];
    __shared__ float Ws2[DUAL ? BK : 1][DUAL ? NOUT : 1];

    const int t = threadIdx.x;
    const int tx = t & 15;                        // column group
    const int ty = t >> 4;                        // row group (0..15)
    const int r0 = ty * 8;
    const int c0 = tx * CPT;
    const int i0 = blockIdx.x * TM;

    float acc[8][CPT];
#pragma unroll
    for (int i = 0; i < 8; i++)
#pragma unroll
        for (int j = 0; j < CPT; j++) acc[i][j] = 0.0f;

    // A loader mapping: 128 rows x 32 k per tile, 16 floats/thread
    const int arow = t >> 1;                      // 0..127
    const int akp = (t & 1) * 16;                 // 0 or 16
    // W loader mapping
    constexpr int TPW = 256 / NOUT;               // threads per weight row: 2 or 4
    constexpr int WE = BK / TPW;                  // elems per thread: 16 or 8
    const int wj = t / TPW;
    const int wk = (t % TPW) * WE;

    for (int k0 = 0; k0 < KD; k0 += BK) {
        {   // stage A (transposed to K-major)
            int gi = i0 + arow;
            float4 v[4] = {{0,0,0,0},{0,0,0,0},{0,0,0,0},{0,0,0,0}};
            if (gi < NN) {
#pragma unroll
                for (int m = 0; m < 4; m++)
                    v[m] = *(const float4*)&A1[(size_t)gi * KD + k0 + akp + m * 4];
            }
#pragma unroll
            for (int m = 0; m < 4; m++) {
                As1[akp + m * 4 + 0][arow] = v[m].x;
                As1[akp + m * 4 + 1][arow] = v[m].y;
                As1[akp + m * 4 + 2][arow] = v[m].z;
                As1[akp + m * 4 + 3][arow] = v[m].w;
            }
            if (DUAL) {
                float4 u[4] = {{0,0,0,0},{0,0,0,0},{0,0,0,0},{0,0,0,0}};
                if (gi < NN) {
#pragma unroll
                    for (int m = 0; m < 4; m++)
                        u[m] = *(const float4*)&A2[(size_t)gi * KD + k0 + akp + m * 4];
                }
#pragma unroll
                for (int m = 0; m < 4; m++) {
                    As2[akp + m * 4 + 0][arow] = u[m].x;
                    As2[akp + m * 4 + 1][arow] = u[m].y;
                    As2[akp + m * 4 + 2][arow] = u[m].z;
                    As2[akp + m * 4 + 3][arow] = u[m].w;
                }
            }
        }
        {   // stage W (transposed to K-major)
#pragma unroll
            for (int m = 0; m < WE; m += 4) {
                float4 w = *(const float4*)&W1[(size_t)wj * KD + k0 + wk + m];
                Ws1[wk + m + 0][wj] = w.x;
                Ws1[wk + m + 1][wj] = w.y;
                Ws1[wk + m + 2][wj] = w.z;
                Ws1[wk + m + 3][wj] = w.w;
            }
            if (DUAL) {
#pragma unroll
                for (int m = 0; m < WE; m += 4) {
                    float4 w = *(const float4*)&W2[(size_t)wj * KD + k0 + wk + m];
                    Ws2[wk + m + 0][wj] = w.x;
                    Ws2[wk + m + 1][wj] = w.y;
                    Ws2[wk + m + 2][wj] = w.z;
                    Ws2[wk + m + 3][wj] = w.w;
                }
            }
        }
        __syncthreads();
#pragma unroll
        for (int kk = 0; kk < BK; kk++) {
            float a[8];
            float4 al = *(const float4*)&As1[kk][r0];
            float4 ah = *(const float4*)&As1[kk][r0 + 4];
            a[0]=al.x; a[1]=al.y; a[2]=al.z; a[3]=al.w;
            a[4]=ah.x; a[5]=ah.y; a[6]=ah.z; a[7]=ah.w;
#pragma unroll
            for (int cc = 0; cc < CPT / 4; cc++) {
                float4 w = *(const float4*)&Ws1[kk][c0 + cc * 4];
                float wv[4] = {w.x, w.y, w.z, w.w};
#pragma unroll
                for (int i = 0; i < 8; i++)
#pragma unroll
                    for (int j = 0; j < 4; j++) acc[i][cc * 4 + j] += a[i] * wv[j];
            }
            if (DUAL) {
                float b[8];
                float4 bl = *(const float4*)&As2[kk][r0];
                float4 bh = *(const float4*)&As2[kk][r0 + 4];
                b[0]=bl.x; b[1]=bl.y; b[2]=bl.z; b[3]=bl.w;
                b[4]=bh.x; b[5]=bh.y; b[6]=bh.z; b[7]=bh.w;
#pragma unroll
                for (int cc = 0; cc < CPT / 4; cc++) {
                    float4 w = *(const float4*)&Ws2[kk][c0 + cc * 4];
                    float wv[4] = {w.x, w.y, w.z, w.w};
#pragma unroll
                    for (int i = 0; i < 8; i++)
#pragma unroll
                        for (int j = 0; j < 4; j++) acc[i][cc * 4 + j] += b[i] * wv[j];
                }
            }
        }
        __syncthreads();
    }
    // epilogue
#pragma unroll
    for (int i = 0; i < 8; i++) {
        int gi = i0 + r0 + i;
        if (gi < NN) {
#pragma unroll
            for (int cc = 0; cc < CPT / 4; cc++) {
                float4 b = *(const float4*)&bias[c0 + cc * 4];
                float4 o;
                o.x = acc[i][cc * 4 + 0] + b.x;
                o.y = acc[i][cc * 4 + 1] + b.y;
                o.z = acc[i][cc * 4 + 2] + b.z;
                o.w = acc[i][cc * 4 + 3] + b.w;
                if (RELU) {
                    o.x = fmaxf(o.x, 0.0f); o.y = fmaxf(o.y, 0.0f);
                    o.z = fmaxf(o.z, 0.0f); o.w = fmaxf(o.w, 0.0f);
                }
                *(float4*)&C[(size_t)gi * NOUT + c0 + cc * 4] = o;
            }
        }
    }
}

// ------------------------------------------------------------------ BN ----
__global__ void bnstats_kernel(const float* __restrict__ Y, float* __restrict__ acc /*[256]*/) {
    int col = threadIdx.x & 127;
    int half = threadIdx.x >> 7;
    float s = 0.0f, q = 0.0f;
    for (int i = blockIdx.x * 2 + half; i < NN; i += gridDim.x * 2) {
        float v = Y[(size_t)i * KD + col];
        s += v;
        q += v * v;
    }
    __shared__ float ls[2][128], lq[2][128];
    ls[half][col] = s;
    lq[half][col] = q;
    __syncthreads();
    if (half == 0) {
        s += ls[1][col];
        q += lq[1][col];
        atomicAdd(&acc[col], s);
        atomicAdd(&acc[128 + col], q);
    }
}

__global__ void bnfinal_kernel(const float* __restrict__ acc, const float* __restrict__ g,
                               const float* __restrict__ b, float* __restrict__ scsh /*[256]*/) {
    int c = threadIdx.x;
    float mean = acc[c] * (1.0f / NN);
    float var = acc[128 + c] * (1.0f / NN) - mean * mean;
    float sc = g[c] * rsqrtf(var + EPSF);
    scsh[c] = sc;
    scsh[128 + c] = b[c] - mean * sc;
}

// out = relu(Y*scale + shift) + R  (float4, in-place safe when out==Y)
__global__ void bnrelures_kernel(const float* __restrict__ Y, const float* __restrict__ R,
                                 const float* __restrict__ scsh, float* __restrict__ out) {
    int idx = blockIdx.x * blockDim.x + threadIdx.x;
    const int total = NN * KD / 4;
    if (idx >= total) return;
    int cg = idx & 31;
    float4 y = ((const float4*)Y)[idx];
    float4 r = ((const float4*)R)[idx];
    float4 sc = ((const float4*)scsh)[cg];
    float4 sh = ((const float4*)scsh)[32 + cg];
    float4 o;
    o.x = fmaxf(y.x * sc.x + sh.x, 0.0f) + r.x;
    o.y = fmaxf(y.y * sc.y + sh.y, 0.0f) + r.y;
    o.z = fmaxf(y.z * sc.z + sh.z, 0.0f) + r.z;
    o.w = fmaxf(y.w * sc.w + sh.w, 0.0f) + r.w;
    ((float4*)out)[idx] = o;
}

// --------------------------------------------------------------- launch ----
extern "C" void kernel_launch(void* const* d_in, const int* in_sizes, int n_in,
                              void* d_out, int out_size, void* d_ws, size_t ws_size,
                              hipStream_t stream) {
    const float* x      = (const float*)d_in[0];
    const int*   ei     = (const int*)d_in[1];
    const int*   e_src  = ei;
    const int*   e_dst  = ei + NE;
    const float* s1_wl  = (const float*)d_in[2];
    const float* s1_wr  = (const float*)d_in[3];
    const float* s1_b   = (const float*)d_in[4];
    const float* s2_wl  = (const float*)d_in[5];
    const float* s2_wr  = (const float*)d_in[6];
    const float* s2_b   = (const float*)d_in[7];
    const float* s3_wl  = (const float*)d_in[8];
    const float* s3_wr  = (const float*)d_in[9];
    const float* s3_b   = (const float*)d_in[10];
    const float* bn1_g  = (const float*)d_in[11];
    const float* bn1_b  = (const float*)d_in[12];
    const float* bn2_g  = (const float*)d_in[13];
    const float* bn2_b  = (const float*)d_in[14];
    const float* res1_w = (const float*)d_in[15];
    const float* res1_b = (const float*)d_in[16];
    const float* res2_w = (const float*)d_in[17];
    const float* res2_b = (const float*)d_in[18];
    const float* ff1_w  = (const float*)d_in[19];
    const float* ff1_b  = (const float*)d_in[20];
    const float* ff2_w  = (const float*)d_in[21];
    const float* ff2_b  = (const float*)d_in[22];
    const float* clf_w  = (const float*)d_in[23];
    const float* clf_b  = (const float*)d_in[24];
    float* out = (float*)d_out;

    // workspace carve-up (256B aligned); peak ~161 MB
    char* w = (char*)d_ws;
    auto alloc = [&](size_t bytes) { char* p = w; w += (bytes + 255) & ~(size_t)255; return p; };
    float* B0        = (float*)alloc((size_t)NN * KD * 4);
    float* B1        = (float*)alloc((size_t)NN * KD * 4);
    float* B2        = (float*)alloc((size_t)NN * KD * 4);
    int*   row_start = (int*)alloc((NN + 1) * 4);
    int*   cursor    = (int*)alloc(NN * 4);        // doubles as cnt
    int*   sorted    = (int*)alloc((size_t)NE * 4);
    float* deg_inv   = (float*)alloc(NN * 4);
    float* bnacc     = (float*)alloc(512 * 4);     // sum1,sq1,sum2,sq2
    float* bnscsh    = (float*)alloc(512 * 4);     // scale1,shift1,scale2,shift2

    const int GE = (NE + 255) / 256;
    const int GN = (NN + 255) / 256;
    const int GG = (NN + 127) / 128;               // gemm blocks
    const int GA = (NN + 7) / 8;                   // aggregate blocks (8 nodes/block)
    const int GV = (NN * KD / 4 + 255) / 256;      // elementwise blocks

    // ---- CSR build (shared across the 3 SAGE layers) ----
    zero_init_kernel<<<GN, 256, 0, stream>>>(cursor, bnacc);
    hist_kernel<<<GE, 256, 0, stream>>>(e_dst, cursor);
    scan_kernel<<<1, 1024, 0, stream>>>(cursor, row_start, deg_inv);
    scatter_kernel<<<GE, 256, 0, stream>>>(e_src, e_dst, cursor, sorted);

    // ---- block 1 ----
    aggregate_kernel<<<GA, 256, 0, stream>>>(x, row_start, sorted, deg_inv, B0);       // mean1
    gemm_kernel<128, false, false><<<GG, 256, 0, stream>>>(x, res1_w, x, res1_w, res1_b, B1);   // res1
    gemm_kernel<128, false, true><<<GG, 256, 0, stream>>>(B0, s1_wl, x, s1_wr, s1_b, B2);       // sage1
    bnstats_kernel<<<512, 256, 0, stream>>>(B2, bnacc);
    bnfinal_kernel<<<1, 128, 0, stream>>>(bnacc, bn1_g, bn1_b, bnscsh);
    bnrelures_kernel<<<GV, 256, 0, stream>>>(B2, B1, bnscsh, B0);                      // h1 -> B0

    // ---- block 2 ----
    aggregate_kernel<<<GA, 256, 0, stream>>>(B0, row_start, sorted, deg_inv, B1);      // mean2
    gemm_kernel<128, false, false><<<GG, 256, 0, stream>>>(B0, res2_w, B0, res2_w, res2_b, B2); // res2
    gemm_kernel<128, false, true><<<GG, 256, 0, stream>>>(B1, s2_wl, B0, s2_wr, s2_b, B0);      // sage2 (in-place safe)
    bnstats_kernel<<<512, 256, 0, stream>>>(B0, bnacc + 256);
    bnfinal_kernel<<<1, 128, 0, stream>>>(bnacc + 256, bn2_g, bn2_b, bnscsh + 256);
    bnrelures_kernel<<<GV, 256, 0, stream>>>(B0, B2, bnscsh + 256, B0);                // h2 -> B0

    // ---- block 3 + head ----
    aggregate_kernel<<<GA, 256, 0, stream>>>(B0, row_start, sorted, deg_inv, B1);      // mean3
    gemm_kernel<128, false, true><<<GG, 256, 0, stream>>>(B1, s3_wl, B0, s3_wr, s3_b, B2);      // sage3
    gemm_kernel<128, true, false><<<GG, 256, 0, stream>>>(B2, ff1_w, B2, ff1_w, ff1_b, B1);     // ff1+relu
    gemm_kernel<128, false, false><<<GG, 256, 0, stream>>>(B1, ff2_w, B1, ff2_w, ff2_b, B0);    // ff2
    gemm_kernel<64, false, false><<<GG, 256, 0, stream>>>(B0, clf_w, B0, clf_w, clf_b, out);    // clf
}

// Round 3
// 1450.122 us; speedup vs baseline: 1.1876x; 1.1876x over previous
//
#include <hip/hip_runtime.h>

#define NN 100000
#define NE 1600000
#define KD 128
#define EPSF 1e-5f
#define SCAN_G ((NN + 255) / 256)   // 391 scan blocks

// ---------------------------------------------------------------- init ----
__global__ void zero_init_kernel(int* __restrict__ cnt, float* __restrict__ bnacc) {
    int i = blockIdx.x * blockDim.x + threadIdx.x;
    if (i < NN) cnt[i] = 0;
    if (i < 512) bnacc[i] = 0.0f;
}

__global__ void hist_kernel(const int* __restrict__ dst, int* __restrict__ cnt) {
    int e = blockIdx.x * blockDim.x + threadIdx.x;
    if (e < NE) atomicAdd(&cnt[dst[e]], 1);
}

// ---- hierarchical scan (3 stages, replaces the single-block 282us scan) ----
// stage 1: per-block sums of counts
__global__ void bsum_kernel(const int* __restrict__ cnt, int* __restrict__ bsum) {
    __shared__ int s[256];
    int i = blockIdx.x * 256 + threadIdx.x;
    s[threadIdx.x] = (i < NN) ? cnt[i] : 0;
    __syncthreads();
#pragma unroll
    for (int off = 128; off > 0; off >>= 1) {
        if (threadIdx.x < off) s[threadIdx.x] += s[threadIdx.x + off];
        __syncthreads();
    }
    if (threadIdx.x == 0) bsum[blockIdx.x] = s[0];
}

// stage 2: single small block scans the 391 block sums (in-place, exclusive)
__global__ void scan_bsum_kernel(int* __restrict__ bsum) {
    __shared__ int s[512];
    int t = threadIdx.x;
    int v = (t < SCAN_G) ? bsum[t] : 0;
    s[t] = v;
    __syncthreads();
    for (int off = 1; off < 512; off <<= 1) {
        int u = (t >= off) ? s[t - off] : 0;
        __syncthreads();
        s[t] += u;
        __syncthreads();
    }
    if (t < SCAN_G) bsum[t] = s[t] - v;   // exclusive
}

// stage 3: per-block local exclusive scan + block offset -> row_start/cursor/deg_inv
__global__ void scan_local_kernel(int* __restrict__ cnt_cursor, const int* __restrict__ bofs,
                                  int* __restrict__ row_start, float* __restrict__ deg_inv) {
    __shared__ int s[256];
    int i = blockIdx.x * 256 + threadIdx.x;
    int c = (i < NN) ? cnt_cursor[i] : 0;
    s[threadIdx.x] = c;
    __syncthreads();
    for (int off = 1; off < 256; off <<= 1) {
        int v = (threadIdx.x >= off) ? s[threadIdx.x - off] : 0;
        __syncthreads();
        s[threadIdx.x] += v;
        __syncthreads();
    }
    int excl = s[threadIdx.x] - c + bofs[blockIdx.x];
    if (i < NN) {
        row_start[i] = excl;
        cnt_cursor[i] = excl;                 // becomes scatter cursor
        deg_inv[i] = 1.0f / (float)(c > 1 ? c : 1);
    }
    if (i == 0) row_start[NN] = NE;
}

__global__ void scatter_kernel(const int* __restrict__ src, const int* __restrict__ dst,
                               int* __restrict__ cursor, int* __restrict__ sorted_src) {
    int e = blockIdx.x * blockDim.x + threadIdx.x;
    if (e < NE) {
        int p = atomicAdd(&cursor[dst[e]], 1);
        sorted_src[p] = src[e];
    }
}

// ------------------------------------------------------------ aggregate ----
// mean over in-neighbors. 8 nodes per 256-thread block; 32 lanes x float4 = 128 dims.
__global__ void aggregate_kernel(const float* __restrict__ X, const int* __restrict__ row_start,
                                 const int* __restrict__ sorted_src,
                                 const float* __restrict__ deg_inv, float* __restrict__ out) {
    int node = blockIdx.x * 8 + (threadIdx.x >> 5);
    int lane = threadIdx.x & 31;
    if (node >= NN) return;
    int e0 = row_start[node];
    int e1 = row_start[node + 1];
    float4 acc = {0.0f, 0.0f, 0.0f, 0.0f};
    for (int e = e0; e < e1; e++) {
        int sn = sorted_src[e];
        float4 v = *(const float4*)&X[(size_t)sn * KD + lane * 4];
        acc.x += v.x; acc.y += v.y; acc.z += v.z; acc.w += v.w;
    }
    float di = deg_inv[node];
    acc.x *= di; acc.y *= di; acc.z *= di; acc.w *= di;
    *(float4*)&out[(size_t)node * KD + lane * 4] = acc;
}

// ----------------------------------------------------------------- GEMM ----
// C[n x NOUT] = act( A1 @ W1^T (+ A2 @ W2^T) + bias ), K=128 each.
// W is [NOUT x 128] row-major (PyTorch layout). TM=128 rows/block, 256 thr,
// 8x(NOUT/16) register tile, A staged K-major in LDS -> b128 fragment reads.
template <int NOUT, bool RELU, bool DUAL>
__global__ __launch_bounds__(256) void gemm_kernel(
    const float* __restrict__ A1, const float* __restrict__ W1,
    const float* __restrict__ A2, const float* __restrict__ W2,
    const float* __restrict__ bias, float* __restrict__ C) {
    constexpr int TM = 128, BK = 32;
    constexpr int CPT = NOUT / 16;               // 8 (NOUT=128) or 4 (NOUT=64)
    __shared__ float As1[BK][TM];
    __shared__ float Ws1[BK][NOUT];
    __shared__ float As2[DUAL ? BK : 1][DUAL ? TM : 1];
    __shared__ float Ws2[DUAL ? BK : 1][DUAL ? NOUT : 1];

    const int t = threadIdx.x;
    const int tx = t & 15;                        // column group
    const int ty = t >> 4;                        // row group (0..15)
    const int r0 = ty * 8;
    const int c0 = tx * CPT;
    const int i0 = blockIdx.x * TM;

    float acc[8][CPT];
#pragma unroll
    for (int i = 0; i < 8; i++)
#pragma unroll
        for (int j = 0; j < CPT; j++) acc[i][j] = 0.0f;

    // A loader mapping: 128 rows x 32 k per tile, 16 floats/thread
    const int arow = t >> 1;                      // 0..127
    const int akp = (t & 1) * 16;                 // 0 or 16
    // W loader mapping
    constexpr int TPW = 256 / NOUT;               // threads per weight row: 2 or 4
    constexpr int WE = BK / TPW;                  // elems per thread: 16 or 8
    const int wj = t / TPW;
    const int wk = (t % TPW) * WE;

    for (int k0 = 0; k0 < KD; k0 += BK) {
        {   // stage A (transposed to K-major)
            int gi = i0 + arow;
            float4 v[4] = {{0,0,0,0},{0,0,0,0},{0,0,0,0},{0,0,0,0}};
            if (gi < NN) {
#pragma unroll
                for (int m = 0; m < 4; m++)
                    v[m] = *(const float4*)&A1[(size_t)gi * KD + k0 + akp + m * 4];
            }
#pragma unroll
            for (int m = 0; m < 4; m++) {
                As1[akp + m * 4 + 0][arow] = v[m].x;
                As1[akp + m * 4 + 1][arow] = v[m].y;
                As1[akp + m * 4 + 2][arow] = v[m].z;
                As1[akp + m * 4 + 3][arow] = v[m].w;
            }
            if (DUAL) {
                float4 u[4] = {{0,0,0,0},{0,0,0,0},{0,0,0,0},{0,0,0,0}};
                if (gi < NN) {
#pragma unroll
                    for (int m = 0; m < 4; m++)
                        u[m] = *(const float4*)&A2[(size_t)gi * KD + k0 + akp + m * 4];
                }
#pragma unroll
                for (int m = 0; m < 4; m++) {
                    As2[akp + m * 4 + 0][arow] = u[m].x;
                    As2[akp + m * 4 + 1][arow] = u[m].y;
                    As2[akp + m * 4 + 2][arow] = u[m].z;
                    As2[akp + m * 4 + 3][arow] = u[m].w;
                }
            }
        }
        {   // stage W (transposed to K-major)
#pragma unroll
            for (int m = 0; m < WE; m += 4) {
                float4 w = *(const float4*)&W1[(size_t)wj * KD + k0 + wk + m];
                Ws1[wk + m + 0][wj] = w.x;
                Ws1[wk + m + 1][wj] = w.y;
                Ws1[wk + m + 2][wj] = w.z;
                Ws1[wk + m + 3][wj] = w.w;
            }
            if (DUAL) {
#pragma unroll
                for (int m = 0; m < WE; m += 4) {
                    float4 w = *(const float4*)&W2[(size_t)wj * KD + k0 + wk + m];
                    Ws2[wk + m + 0][wj] = w.x;
                    Ws2[wk + m + 1][wj] = w.y;
                    Ws2[wk + m + 2][wj] = w.z;
                    Ws2[wk + m + 3][wj] = w.w;
                }
            }
        }
        __syncthreads();
#pragma unroll
        for (int kk = 0; kk < BK; kk++) {
            float a[8];
            float4 al = *(const float4*)&As1[kk][r0];
            float4 ah = *(const float4*)&As1[kk][r0 + 4];
            a[0]=al.x; a[1]=al.y; a[2]=al.z; a[3]=al.w;
            a[4]=ah.x; a[5]=ah.y; a[6]=ah.z; a[7]=ah.w;
#pragma unroll
            for (int cc = 0; cc < CPT / 4; cc++) {
                float4 w = *(const float4*)&Ws1[kk][c0 + cc * 4];
                float wv[4] = {w.x, w.y, w.z, w.w};
#pragma unroll
                for (int i = 0; i < 8; i++)
#pragma unroll
                    for (int j = 0; j < 4; j++) acc[i][cc * 4 + j] += a[i] * wv[j];
            }
            if (DUAL) {
                float b[8];
                float4 bl = *(const float4*)&As2[kk][r0];
                float4 bh = *(const float4*)&As2[kk][r0 + 4];
                b[0]=bl.x; b[1]=bl.y; b[2]=bl.z; b[3]=bl.w;
                b[4]=bh.x; b[5]=bh.y; b[6]=bh.z; b[7]=bh.w;
#pragma unroll
                for (int cc = 0; cc < CPT / 4; cc++) {
                    float4 w = *(const float4*)&Ws2[kk][c0 + cc * 4];
                    float wv[4] = {w.x, w.y, w.z, w.w};
#pragma unroll
                    for (int i = 0; i < 8; i++)
#pragma unroll
                        for (int j = 0; j < 4; j++) acc[i][cc * 4 + j] += b[i] * wv[j];
                }
            }
        }
        __syncthreads();
    }
    // epilogue
#pragma unroll
    for (int i = 0; i < 8; i++) {
        int gi = i0 + r0 + i;
        if (gi < NN) {
#pragma unroll
            for (int cc = 0; cc < CPT / 4; cc++) {
                float4 b = *(const float4*)&bias[c0 + cc * 4];
                float4 o;
                o.x = acc[i][cc * 4 + 0] + b.x;
                o.y = acc[i][cc * 4 + 1] + b.y;
                o.z = acc[i][cc * 4 + 2] + b.z;
                o.w = acc[i][cc * 4 + 3] + b.w;
                if (RELU) {
                    o.x = fmaxf(o.x, 0.0f); o.y = fmaxf(o.y, 0.0f);
                    o.z = fmaxf(o.z, 0.0f); o.w = fmaxf(o.w, 0.0f);
                }
                *(float4*)&C[(size_t)gi * NOUT + c0 + cc * 4] = o;
            }
        }
    }
}

// ------------------------------------------------------------------ BN ----
__global__ void bnstats_kernel(const float* __restrict__ Y, float* __restrict__ acc /*[256]*/) {
    int col = threadIdx.x & 127;
    int half = threadIdx.x >> 7;
    float s = 0.0f, q = 0.0f;
    for (int i = blockIdx.x * 2 + half; i < NN; i += gridDim.x * 2) {
        float v = Y[(size_t)i * KD + col];
        s += v;
        q += v * v;
    }
    __shared__ float ls[2][128], lq[2][128];
    ls[half][col] = s;
    lq[half][col] = q;
    __syncthreads();
    if (half == 0) {
        s += ls[1][col];
        q += lq[1][col];
        atomicAdd(&acc[col], s);
        atomicAdd(&acc[128 + col], q);
    }
}

__global__ void bnfinal_kernel(const float* __restrict__ acc, const float* __restrict__ g,
                               const float* __restrict__ b, float* __restrict__ scsh /*[256]*/) {
    int c = threadIdx.x;
    float mean = acc[c] * (1.0f / NN);
    float var = acc[128 + c] * (1.0f / NN) - mean * mean;
    float sc = g[c] * rsqrtf(var + EPSF);
    scsh[c] = sc;
    scsh[128 + c] = b[c] - mean * sc;
}

// out = relu(Y*scale + shift) + R  (float4, in-place safe when out==Y)
__global__ void bnrelures_kernel(const float* __restrict__ Y, const float* __restrict__ R,
                                 const float* __restrict__ scsh, float* __restrict__ out) {
    int idx = blockIdx.x * blockDim.x + threadIdx.x;
    const int total = NN * KD / 4;
    if (idx >= total) return;
    int cg = idx & 31;
    float4 y = ((const float4*)Y)[idx];
    float4 r = ((const float4*)R)[idx];
    float4 sc = ((const float4*)scsh)[cg];
    float4 sh = ((const float4*)scsh)[32 + cg];
    float4 o;
    o.x = fmaxf(y.x * sc.x + sh.x, 0.0f) + r.x;
    o.y = fmaxf(y.y * sc.y + sh.y, 0.0f) + r.y;
    o.z = fmaxf(y.z * sc.z + sh.z, 0.0f) + r.z;
    o.w = fmaxf(y.w * sc.w + sh.w, 0.0f) + r.w;
    ((float4*)out)[idx] = o;
}

// --------------------------------------------------------------- launch ----
extern "C" void kernel_launch(void* const* d_in, const int* in_sizes, int n_in,
                              void* d_out, int out_size, void* d_ws, size_t ws_size,
                              hipStream_t stream) {
    const float* x      = (const float*)d_in[0];
    const int*   ei     = (const int*)d_in[1];
    const int*   e_src  = ei;
    const int*   e_dst  = ei + NE;
    const float* s1_wl  = (const float*)d_in[2];
    const float* s1_wr  = (const float*)d_in[3];
    const float* s1_b   = (const float*)d_in[4];
    const float* s2_wl  = (const float*)d_in[5];
    const float* s2_wr  = (const float*)d_in[6];
    const float* s2_b   = (const float*)d_in[7];
    const float* s3_wl  = (const float*)d_in[8];
    const float* s3_wr  = (const float*)d_in[9];
    const float* s3_b   = (const float*)d_in[10];
    const float* bn1_g  = (const float*)d_in[11];
    const float* bn1_b  = (const float*)d_in[12];
    const float* bn2_g  = (const float*)d_in[13];
    const float* bn2_b  = (const float*)d_in[14];
    const float* res1_w = (const float*)d_in[15];
    const float* res1_b = (const float*)d_in[16];
    const float* res2_w = (const float*)d_in[17];
    const float* res2_b = (const float*)d_in[18];
    const float* ff1_w  = (const float*)d_in[19];
    const float* ff1_b  = (const float*)d_in[20];
    const float* ff2_w  = (const float*)d_in[21];
    const float* ff2_b  = (const float*)d_in[22];
    const float* clf_w  = (const float*)d_in[23];
    const float* clf_b  = (const float*)d_in[24];
    float* out = (float*)d_out;

    // workspace carve-up (256B aligned); peak ~161 MB
    char* w = (char*)d_ws;
    auto alloc = [&](size_t bytes) { char* p = w; w += (bytes + 255) & ~(size_t)255; return p; };
    float* B0        = (float*)alloc((size_t)NN * KD * 4);
    float* B1        = (float*)alloc((size_t)NN * KD * 4);
    float* B2        = (float*)alloc((size_t)NN * KD * 4);
    int*   row_start = (int*)alloc((NN + 1) * 4);
    int*   cursor    = (int*)alloc(NN * 4);        // doubles as cnt
    int*   sorted    = (int*)alloc((size_t)NE * 4);
    float* deg_inv   = (float*)alloc(NN * 4);
    float* bnacc     = (float*)alloc(512 * 4);     // sum1,sq1,sum2,sq2
    float* bnscsh    = (float*)alloc(512 * 4);     // scale1,shift1,scale2,shift2
    int*   bsum      = (int*)alloc(SCAN_G * 4);    // scan block sums

    const int GE = (NE + 255) / 256;
    const int GN = (NN + 255) / 256;
    const int GG = (NN + 127) / 128;               // gemm blocks
    const int GA = (NN + 7) / 8;                   // aggregate blocks (8 nodes/block)
    const int GV = (NN * KD / 4 + 255) / 256;      // elementwise blocks

    // ---- CSR build (shared across the 3 SAGE layers) ----
    zero_init_kernel<<<GN, 256, 0, stream>>>(cursor, bnacc);
    hist_kernel<<<GE, 256, 0, stream>>>(e_dst, cursor);
    bsum_kernel<<<SCAN_G, 256, 0, stream>>>(cursor, bsum);
    scan_bsum_kernel<<<1, 512, 0, stream>>>(bsum);
    scan_local_kernel<<<SCAN_G, 256, 0, stream>>>(cursor, bsum, row_start, deg_inv);
    scatter_kernel<<<GE, 256, 0, stream>>>(e_src, e_dst, cursor, sorted);

    // ---- block 1 ----
    aggregate_kernel<<<GA, 256, 0, stream>>>(x, row_start, sorted, deg_inv, B0);       // mean1
    gemm_kernel<128, false, false><<<GG, 256, 0, stream>>>(x, res1_w, x, res1_w, res1_b, B1);   // res1
    gemm_kernel<128, false, true><<<GG, 256, 0, stream>>>(B0, s1_wl, x, s1_wr, s1_b, B2);       // sage1
    bnstats_kernel<<<512, 256, 0, stream>>>(B2, bnacc);
    bnfinal_kernel<<<1, 128, 0, stream>>>(bnacc, bn1_g, bn1_b, bnscsh);
    bnrelures_kernel<<<GV, 256, 0, stream>>>(B2, B1, bnscsh, B0);                      // h1 -> B0

    // ---- block 2 ----
    aggregate_kernel<<<GA, 256, 0, stream>>>(B0, row_start, sorted, deg_inv, B1);      // mean2
    gemm_kernel<128, false, false><<<GG, 256, 0, stream>>>(B0, res2_w, B0, res2_w, res2_b, B2); // res2
    gemm_kernel<128, false, true><<<GG, 256, 0, stream>>>(B1, s2_wl, B0, s2_wr, s2_b, B0);      // sage2 (in-place safe)
    bnstats_kernel<<<512, 256, 0, stream>>>(B0, bnacc + 256);
    bnfinal_kernel<<<1, 128, 0, stream>>>(bnacc + 256, bn2_g, bn2_b, bnscsh + 256);
    bnrelures_kernel<<<GV, 256, 0, stream>>>(B0, B2, bnscsh + 256, B0);                // h2 -> B0

    // ---- block 3 + head ----
    aggregate_kernel<<<GA, 256, 0, stream>>>(B0, row_start, sorted, deg_inv, B1);      // mean3
    gemm_kernel<128, false, true><<<GG, 256, 0, stream>>>(B1, s3_wl, B0, s3_wr, s3_b, B2);      // sage3
    gemm_kernel<128, true, false><<<GG, 256, 0, stream>>>(B2, ff1_w, B2, ff1_w, ff1_b, B1);     // ff1+relu
    gemm_kernel<128, false, false><<<GG, 256, 0, stream>>>(B1, ff2_w, B1, ff2_w, ff2_b, B0);    // ff2
    gemm_kernel<64, false, false><<<GG, 256, 0, stream>>>(B0, clf_w, B0, clf_w, clf_b, out);    // clf
}

// Round 4
// 1087.393 us; speedup vs baseline: 1.5837x; 1.3336x over previous
//
#include <hip/hip_runtime.h>

#define NN 100000
#define NE 1600000
#define KD 128
#define EPSF 1e-5f
#define SCAN_G ((NN + 255) / 256)   // 391 scan blocks

typedef __attribute__((ext_vector_type(8))) short bf16x8;
typedef __attribute__((ext_vector_type(4))) float f32x4;

// ---- bf16 split helpers (RNE) ----
__device__ __forceinline__ unsigned short f2bf(float f) {
    unsigned u = __float_as_uint(f);
    u += 0x7FFFu + ((u >> 16) & 1u);
    return (unsigned short)(u >> 16);
}
__device__ __forceinline__ float bfh2f(unsigned short h) {
    return __uint_as_float(((unsigned)h) << 16);
}
// packed fp32 ~= hi + lo, stored as (hi<<16)|lo
__device__ __forceinline__ unsigned packf(float f) {
    unsigned short h = f2bf(f);
    float lo = f - bfh2f(h);
    unsigned short l = f2bf(lo);
    return ((unsigned)h << 16) | (unsigned)l;
}
__device__ __forceinline__ float unpackf(unsigned p) {
    return __uint_as_float(p & 0xFFFF0000u) + __uint_as_float(p << 16);
}

// ---------------------------------------------------------------- init ----
__global__ void zero_init_kernel(int* __restrict__ cnt, float* __restrict__ bnacc) {
    int i = blockIdx.x * blockDim.x + threadIdx.x;
    if (i < NN) cnt[i] = 0;
    if (i < 512) bnacc[i] = 0.0f;
}

__global__ void hist_kernel(const int* __restrict__ dst, int* __restrict__ cnt) {
    int e = blockIdx.x * blockDim.x + threadIdx.x;
    if (e < NE) atomicAdd(&cnt[dst[e]], 1);
}

// ---- hierarchical scan ----
__global__ void bsum_kernel(const int* __restrict__ cnt, int* __restrict__ bsum) {
    __shared__ int s[256];
    int i = blockIdx.x * 256 + threadIdx.x;
    s[threadIdx.x] = (i < NN) ? cnt[i] : 0;
    __syncthreads();
#pragma unroll
    for (int off = 128; off > 0; off >>= 1) {
        if (threadIdx.x < off) s[threadIdx.x] += s[threadIdx.x + off];
        __syncthreads();
    }
    if (threadIdx.x == 0) bsum[blockIdx.x] = s[0];
}

__global__ void scan_bsum_kernel(int* __restrict__ bsum) {
    __shared__ int s[512];
    int t = threadIdx.x;
    int v = (t < SCAN_G) ? bsum[t] : 0;
    s[t] = v;
    __syncthreads();
    for (int off = 1; off < 512; off <<= 1) {
        int u = (t >= off) ? s[t - off] : 0;
        __syncthreads();
        s[t] += u;
        __syncthreads();
    }
    if (t < SCAN_G) bsum[t] = s[t] - v;   // exclusive
}

__global__ void scan_local_kernel(int* __restrict__ cnt_cursor, const int* __restrict__ bofs,
                                  int* __restrict__ row_start, float* __restrict__ deg_inv) {
    __shared__ int s[256];
    int i = blockIdx.x * 256 + threadIdx.x;
    int c = (i < NN) ? cnt_cursor[i] : 0;
    s[threadIdx.x] = c;
    __syncthreads();
    for (int off = 1; off < 256; off <<= 1) {
        int v = (threadIdx.x >= off) ? s[threadIdx.x - off] : 0;
        __syncthreads();
        s[threadIdx.x] += v;
        __syncthreads();
    }
    int excl = s[threadIdx.x] - c + bofs[blockIdx.x];
    if (i < NN) {
        row_start[i] = excl;
        cnt_cursor[i] = excl;
        deg_inv[i] = 1.0f / (float)(c > 1 ? c : 1);
    }
    if (i == 0) row_start[NN] = NE;
}

__global__ void scatter_kernel(const int* __restrict__ src, const int* __restrict__ dst,
                               int* __restrict__ cursor, int* __restrict__ sorted_src) {
    int e = blockIdx.x * blockDim.x + threadIdx.x;
    if (e < NE) {
        int p = atomicAdd(&cursor[dst[e]], 1);
        sorted_src[p] = src[e];
    }
}

// ---------------------------------------------------------- converters ----
// fp32 -> packed hi/lo bf16 (per float4)
__global__ void pack_kernel(const float* __restrict__ X, unsigned* __restrict__ P, int n4) {
    int i = blockIdx.x * 256 + threadIdx.x;
    if (i >= n4) return;
    float4 v = ((const float4*)X)[i];
    uint4 o;
    o.x = packf(v.x); o.y = packf(v.y); o.z = packf(v.z); o.w = packf(v.w);
    ((uint4*)P)[i] = o;
}

// all 11 weight matrices -> packed, contiguous at j*16384 (clf last, 8192)
__global__ void wconv_kernel(const float* w0, const float* w1, const float* w2,
                             const float* w3, const float* w4, const float* w5,
                             const float* w6, const float* w7, const float* w8,
                             const float* w9, const float* w10, unsigned* __restrict__ P) {
    int i = blockIdx.x * 256 + threadIdx.x;  // float4 index
    if (i >= 43008) return;                  // 10*4096 + 2048
    int seg = i >> 12;
    const float* srcs[11] = {w0, w1, w2, w3, w4, w5, w6, w7, w8, w9, w10};
    const float* s = srcs[seg];
    int off = i - (seg << 12);
    float4 v = ((const float4*)s)[off];
    uint4 o;
    o.x = packf(v.x); o.y = packf(v.y); o.z = packf(v.z); o.w = packf(v.w);
    ((uint4*)P)[i] = o;
}

// ------------------------------------------------------------ aggregate ----
// mean over in-neighbors -> packed output. 8 nodes/block, 32 lanes x 4 dims.
template <bool PACKED>
__global__ void aggregate_kernel(const float* __restrict__ Xf, const unsigned* __restrict__ Xp,
                                 const int* __restrict__ row_start,
                                 const int* __restrict__ sorted_src,
                                 const float* __restrict__ deg_inv, unsigned* __restrict__ Mp) {
    int node = blockIdx.x * 8 + (threadIdx.x >> 5);
    int lane = threadIdx.x & 31;
    if (node >= NN) return;
    int e0 = row_start[node];
    int e1 = row_start[node + 1];
    float4 acc = {0.0f, 0.0f, 0.0f, 0.0f};
    for (int e = e0; e < e1; e++) {
        int sn = sorted_src[e];
        if (PACKED) {
            uint4 u = *(const uint4*)&Xp[(size_t)sn * KD + lane * 4];
            acc.x += unpackf(u.x); acc.y += unpackf(u.y);
            acc.z += unpackf(u.z); acc.w += unpackf(u.w);
        } else {
            float4 v = *(const float4*)&Xf[(size_t)sn * KD + lane * 4];
            acc.x += v.x; acc.y += v.y; acc.z += v.z; acc.w += v.w;
        }
    }
    float di = deg_inv[node];
    uint4 o;
    o.x = packf(acc.x * di); o.y = packf(acc.y * di);
    o.z = packf(acc.z * di); o.w = packf(acc.w * di);
    *(uint4*)&Mp[(size_t)node * KD + lane * 4] = o;
}

// ----------------------------------------------------- MFMA split GEMM ----
// C[n x NOUT] = act( A1@W1^T (+ A2@W2^T) + bias ); inputs packed hi/lo bf16.
// Split product: Ah*Wh + Ah*Wl + Al*Wh (error ~2^-17 rel).
// Block: 128 rows x NOUT cols, 256 thr (4 waves), per-wave 64x64 (or 32x64),
// mfma_f32_16x16x32_bf16; K-step 32; DUAL = 8 sequential steps (concat K=256).
template <int NOUT, bool RELU, bool DUAL, bool HILO>
__global__ __launch_bounds__(256, 2) void mgemm_kernel(
    const unsigned* __restrict__ A1, const unsigned* __restrict__ W1,
    const unsigned* __restrict__ A2, const unsigned* __restrict__ W2,
    const float* __restrict__ bias, float* __restrict__ Cf, unsigned* __restrict__ Cp) {
    constexpr int LDA = 40;                       // 32 + 8 pad: 2-way max bank aliasing
    __shared__ __align__(16) unsigned short Ash[128 * LDA];
    __shared__ __align__(16) unsigned short Asl[128 * LDA];
    __shared__ __align__(16) unsigned short Wsh[NOUT * LDA];
    __shared__ __align__(16) unsigned short Wsl[NOUT * LDA];

    const int t = threadIdx.x;
    const int i0 = blockIdx.x * 128;
    // A stage mapping: 128 rows x 32 k, 16 elems/thread
    const int arow = t >> 1;
    const int akp = (t & 1) * 16;
    // W stage mapping
    const int wrow = (NOUT == 128) ? (t >> 1) : (t >> 2);
    const int wkp = (NOUT == 128) ? (t & 1) * 16 : (t & 3) * 8;
    constexpr int WLOAD = (NOUT == 128) ? 16 : 8;   // elems/thread

    // compute mapping
    const int w = t >> 6, lane = t & 63, quad = lane >> 4, mm = lane & 15;
    constexpr int MT = (NOUT == 128) ? 4 : 2;
    constexpr int NT = 4;
    const int rowb = (NOUT == 128) ? (w >> 1) * 64 : w * 32;
    const int colb = (NOUT == 128) ? (w & 1) * 64 : 0;

    f32x4 acc[MT][NT] = {};

    constexpr int STEPS = DUAL ? 8 : 4;
    for (int s = 0; s < STEPS; s++) {
        const unsigned* Ap = (!DUAL || s < 4) ? A1 : A2;
        const unsigned* Wp = (!DUAL || s < 4) ? W1 : W2;
        const int k0 = (s & 3) * 32;
        {   // stage A tile: split packed into hi/lo planes
            int gi = i0 + arow;
            uint4 u[4] = {{0,0,0,0},{0,0,0,0},{0,0,0,0},{0,0,0,0}};
            if (gi < NN) {
                const unsigned* p = Ap + (size_t)gi * KD + k0 + akp;
#pragma unroll
                for (int m = 0; m < 4; m++) u[m] = *(const uint4*)(p + m * 4);
            }
#pragma unroll
            for (int m = 0; m < 4; m++) {
                unsigned* dh = (unsigned*)&Ash[arow * LDA + akp + m * 4];
                unsigned* dl = (unsigned*)&Asl[arow * LDA + akp + m * 4];
                dh[0] = (u[m].x >> 16) | (u[m].y & 0xFFFF0000u);
                dh[1] = (u[m].z >> 16) | (u[m].w & 0xFFFF0000u);
                dl[0] = (u[m].x & 0xFFFFu) | (u[m].y << 16);
                dl[1] = (u[m].z & 0xFFFFu) | (u[m].w << 16);
            }
        }
        {   // stage W tile
            const unsigned* p = Wp + (size_t)wrow * KD + k0 + wkp;
            uint4 u[WLOAD / 4];
#pragma unroll
            for (int m = 0; m < WLOAD / 4; m++) u[m] = *(const uint4*)(p + m * 4);
#pragma unroll
            for (int m = 0; m < WLOAD / 4; m++) {
                unsigned* dh = (unsigned*)&Wsh[wrow * LDA + wkp + m * 4];
                unsigned* dl = (unsigned*)&Wsl[wrow * LDA + wkp + m * 4];
                dh[0] = (u[m].x >> 16) | (u[m].y & 0xFFFF0000u);
                dh[1] = (u[m].z >> 16) | (u[m].w & 0xFFFF0000u);
                dl[0] = (u[m].x & 0xFFFFu) | (u[m].y << 16);
                dl[1] = (u[m].z & 0xFFFFu) | (u[m].w << 16);
            }
        }
        __syncthreads();
        // fragments + MFMA
        bf16x8 ah[MT], al[MT];
#pragma unroll
        for (int mt = 0; mt < MT; mt++) {
            int off = (rowb + mt * 16 + mm) * LDA + quad * 8;
            ah[mt] = *(const bf16x8*)&Ash[off];
            al[mt] = *(const bf16x8*)&Asl[off];
        }
#pragma unroll
        for (int ng = 0; ng < NT; ng += 2) {
            bf16x8 bh[2], bl[2];
#pragma unroll
            for (int j = 0; j < 2; j++) {
                int off = (colb + (ng + j) * 16 + mm) * LDA + quad * 8;
                bh[j] = *(const bf16x8*)&Wsh[off];
                bl[j] = *(const bf16x8*)&Wsl[off];
            }
#pragma unroll
            for (int mt = 0; mt < MT; mt++)
#pragma unroll
                for (int j = 0; j < 2; j++) {
                    acc[mt][ng + j] = __builtin_amdgcn_mfma_f32_16x16x32_bf16(
                        ah[mt], bh[j], acc[mt][ng + j], 0, 0, 0);
                    acc[mt][ng + j] = __builtin_amdgcn_mfma_f32_16x16x32_bf16(
                        ah[mt], bl[j], acc[mt][ng + j], 0, 0, 0);
                    acc[mt][ng + j] = __builtin_amdgcn_mfma_f32_16x16x32_bf16(
                        al[mt], bh[j], acc[mt][ng + j], 0, 0, 0);
                }
        }
        __syncthreads();
    }
    // epilogue: C/D layout col=lane&15, row=quad*4+reg
#pragma unroll
    for (int mt = 0; mt < MT; mt++)
#pragma unroll
        for (int nt = 0; nt < NT; nt++) {
            int col = colb + nt * 16 + mm;
            float bv = bias[col];
#pragma unroll
            for (int r = 0; r < 4; r++) {
                int row = i0 + rowb + mt * 16 + quad * 4 + r;
                if (row < NN) {
                    float v = acc[mt][nt][r] + bv;
                    if (RELU) v = fmaxf(v, 0.0f);
                    if (HILO) Cp[(size_t)row * NOUT + col] = packf(v);
                    else      Cf[(size_t)row * NOUT + col] = v;
                }
            }
        }
}

// ------------------------------------------------------------------ BN ----
__global__ void bnstats_kernel(const float* __restrict__ Y, float* __restrict__ acc) {
    int col = threadIdx.x & 127;
    int half = threadIdx.x >> 7;
    float s = 0.0f, q = 0.0f;
    for (int i = blockIdx.x * 2 + half; i < NN; i += gridDim.x * 2) {
        float v = Y[(size_t)i * KD + col];
        s += v;
        q += v * v;
    }
    __shared__ float ls[2][128], lq[2][128];
    ls[half][col] = s;
    lq[half][col] = q;
    __syncthreads();
    if (half == 0) {
        s += ls[1][col];
        q += lq[1][col];
        atomicAdd(&acc[col], s);
        atomicAdd(&acc[128 + col], q);
    }
}

__global__ void bnfinal_kernel(const float* __restrict__ acc, const float* __restrict__ g,
                               const float* __restrict__ b, float* __restrict__ scsh) {
    int c = threadIdx.x;
    float mean = acc[c] * (1.0f / NN);
    float var = acc[128 + c] * (1.0f / NN) - mean * mean;
    float sc = g[c] * rsqrtf(var + EPSF);
    scsh[c] = sc;
    scsh[128 + c] = b[c] - mean * sc;
}

// out_packed = pack( relu(Y*scale + shift) + R )
__global__ void bnrelures_kernel(const float* __restrict__ Y, const float* __restrict__ R,
                                 const float* __restrict__ scsh, unsigned* __restrict__ Op) {
    int idx = blockIdx.x * blockDim.x + threadIdx.x;
    const int total = NN * KD / 4;
    if (idx >= total) return;
    int cg = idx & 31;
    float4 y = ((const float4*)Y)[idx];
    float4 r = ((const float4*)R)[idx];
    float4 sc = ((const float4*)scsh)[cg];
    float4 sh = ((const float4*)scsh)[32 + cg];
    uint4 o;
    o.x = packf(fmaxf(y.x * sc.x + sh.x, 0.0f) + r.x);
    o.y = packf(fmaxf(y.y * sc.y + sh.y, 0.0f) + r.y);
    o.z = packf(fmaxf(y.z * sc.z + sh.z, 0.0f) + r.z);
    o.w = packf(fmaxf(y.w * sc.w + sh.w, 0.0f) + r.w);
    ((uint4*)Op)[idx] = o;
}

// --------------------------------------------------------------- launch ----
extern "C" void kernel_launch(void* const* d_in, const int* in_sizes, int n_in,
                              void* d_out, int out_size, void* d_ws, size_t ws_size,
                              hipStream_t stream) {
    const float* x      = (const float*)d_in[0];
    const int*   ei     = (const int*)d_in[1];
    const int*   e_src  = ei;
    const int*   e_dst  = ei + NE;
    const float* s1_wl  = (const float*)d_in[2];
    const float* s1_wr  = (const float*)d_in[3];
    const float* s1_b   = (const float*)d_in[4];
    const float* s2_wl  = (const float*)d_in[5];
    const float* s2_wr  = (const float*)d_in[6];
    const float* s2_b   = (const float*)d_in[7];
    const float* s3_wl  = (const float*)d_in[8];
    const float* s3_wr  = (const float*)d_in[9];
    const float* s3_b   = (const float*)d_in[10];
    const float* bn1_g  = (const float*)d_in[11];
    const float* bn1_b  = (const float*)d_in[12];
    const float* bn2_g  = (const float*)d_in[13];
    const float* bn2_b  = (const float*)d_in[14];
    const float* res1_w = (const float*)d_in[15];
    const float* res1_b = (const float*)d_in[16];
    const float* res2_w = (const float*)d_in[17];
    const float* res2_b = (const float*)d_in[18];
    const float* ff1_w  = (const float*)d_in[19];
    const float* ff1_b  = (const float*)d_in[20];
    const float* ff2_w  = (const float*)d_in[21];
    const float* ff2_b  = (const float*)d_in[22];
    const float* clf_w  = (const float*)d_in[23];
    const float* clf_b  = (const float*)d_in[24];
    float* out = (float*)d_out;

    // workspace carve-up (256B aligned); peak ~214 MB
    char* w = (char*)d_ws;
    auto alloc = [&](size_t bytes) { char* p = w; w += (bytes + 255) & ~(size_t)255; return p; };
    float*    B0        = (float*)alloc((size_t)NN * KD * 4);     // fp32 sage-out
    float*    B1        = (float*)alloc((size_t)NN * KD * 4);     // fp32 residual
    unsigned* P0        = (unsigned*)alloc((size_t)NN * KD * 4);  // packed hi/lo
    unsigned* P1        = (unsigned*)alloc((size_t)NN * KD * 4);  // packed hi/lo
    int*      row_start = (int*)alloc((NN + 1) * 4);
    int*      cursor    = (int*)alloc(NN * 4);
    int*      sorted    = (int*)alloc((size_t)NE * 4);
    float*    deg_inv   = (float*)alloc(NN * 4);
    float*    bnacc     = (float*)alloc(512 * 4);
    float*    bnscsh    = (float*)alloc(512 * 4);
    int*      bsum      = (int*)alloc(SCAN_G * 4);
    unsigned* Wpk       = (unsigned*)alloc(172032 * 4);           // 11 packed weights

    const int GE = (NE + 255) / 256;
    const int GN = (NN + 255) / 256;
    const int GG = (NN + 127) / 128;
    const int GA = (NN + 7) / 8;
    const int GV = (NN * KD / 4 + 255) / 256;

    // ---- CSR build ----
    zero_init_kernel<<<GN, 256, 0, stream>>>(cursor, bnacc);
    hist_kernel<<<GE, 256, 0, stream>>>(e_dst, cursor);
    bsum_kernel<<<SCAN_G, 256, 0, stream>>>(cursor, bsum);
    scan_bsum_kernel<<<1, 512, 0, stream>>>(bsum);
    scan_local_kernel<<<SCAN_G, 256, 0, stream>>>(cursor, bsum, row_start, deg_inv);
    scatter_kernel<<<GE, 256, 0, stream>>>(e_src, e_dst, cursor, sorted);

    // ---- conversions ----
    pack_kernel<<<(NN * KD / 4 + 255) / 256, 256, 0, stream>>>(x, P0, NN * KD / 4); // x -> P0
    wconv_kernel<<<(43008 + 255) / 256, 256, 0, stream>>>(
        res1_w, s1_wl, s1_wr, res2_w, s2_wl, s2_wr, s3_wl, s3_wr, ff1_w, ff2_w, clf_w, Wpk);

    // ---- block 1 ----
    aggregate_kernel<false><<<GA, 256, 0, stream>>>(x, nullptr, row_start, sorted, deg_inv, P1); // mean1
    mgemm_kernel<128, false, false, false><<<GG, 256, 0, stream>>>(
        P0, Wpk + 0 * 16384, nullptr, nullptr, res1_b, B1, nullptr);                 // res1
    mgemm_kernel<128, false, true, false><<<GG, 256, 0, stream>>>(
        P1, Wpk + 1 * 16384, P0, Wpk + 2 * 16384, s1_b, B0, nullptr);                // sage1
    bnstats_kernel<<<512, 256, 0, stream>>>(B0, bnacc);
    bnfinal_kernel<<<1, 128, 0, stream>>>(bnacc, bn1_g, bn1_b, bnscsh);
    bnrelures_kernel<<<GV, 256, 0, stream>>>(B0, B1, bnscsh, P0);                    // h1 -> P0

    // ---- block 2 ----
    aggregate_kernel<true><<<GA, 256, 0, stream>>>(nullptr, P0, row_start, sorted, deg_inv, P1); // mean2
    mgemm_kernel<128, false, false, false><<<GG, 256, 0, stream>>>(
        P0, Wpk + 3 * 16384, nullptr, nullptr, res2_b, B1, nullptr);                 // res2
    mgemm_kernel<128, false, true, false><<<GG, 256, 0, stream>>>(
        P1, Wpk + 4 * 16384, P0, Wpk + 5 * 16384, s2_b, B0, nullptr);                // sage2
    bnstats_kernel<<<512, 256, 0, stream>>>(B0, bnacc + 256);
    bnfinal_kernel<<<1, 128, 0, stream>>>(bnacc + 256, bn2_g, bn2_b, bnscsh + 256);
    bnrelures_kernel<<<GV, 256, 0, stream>>>(B0, B1, bnscsh + 256, P0);              // h2 -> P0

    // ---- block 3 + head ----
    aggregate_kernel<true><<<GA, 256, 0, stream>>>(nullptr, P0, row_start, sorted, deg_inv, P1); // mean3
    mgemm_kernel<128, false, true, true><<<GG, 256, 0, stream>>>(
        P1, Wpk + 6 * 16384, P0, Wpk + 7 * 16384, s3_b, nullptr, P0);                // sage3 -> P0 (in-place safe)
    mgemm_kernel<128, true, false, true><<<GG, 256, 0, stream>>>(
        P0, Wpk + 8 * 16384, nullptr, nullptr, ff1_b, nullptr, P1);                  // ff1+relu -> P1
    mgemm_kernel<128, false, false, true><<<GG, 256, 0, stream>>>(
        P1, Wpk + 9 * 16384, nullptr, nullptr, ff2_b, nullptr, P0);                  // ff2 -> P0
    mgemm_kernel<64, false, false, false><<<GG, 256, 0, stream>>>(
        P0, Wpk + 10 * 16384, nullptr, nullptr, clf_b, out, nullptr);                // clf -> out
}

// Round 5
// 1048.391 us; speedup vs baseline: 1.6427x; 1.0372x over previous
//
#include <hip/hip_runtime.h>

#define NN 100000
#define NE 1600000
#define KD 128
#define EPSF 1e-5f
#define SCAN_G ((NN + 255) / 256)   // 391 scan blocks
#define RNG 8                       // dst-range partitions (≈1 per XCD)
#define BPR 784                     // blocks per range
#define ECH ((NE + BPR - 1) / BPR)  // edges per block slice (2041)
#define RSZ (NN / RNG)              // 12500 nodes per range

typedef __attribute__((ext_vector_type(8))) short bf16x8;
typedef __attribute__((ext_vector_type(4))) float f32x4;

// ---- bf16 split helpers (RNE) ----
__device__ __forceinline__ unsigned short f2bf(float f) {
    unsigned u = __float_as_uint(f);
    u += 0x7FFFu + ((u >> 16) & 1u);
    return (unsigned short)(u >> 16);
}
__device__ __forceinline__ float bfh2f(unsigned short h) {
    return __uint_as_float(((unsigned)h) << 16);
}
// packed fp32 ~= hi + lo, stored as (hi<<16)|lo
__device__ __forceinline__ unsigned packf(float f) {
    unsigned short h = f2bf(f);
    float lo = f - bfh2f(h);
    unsigned short l = f2bf(lo);
    return ((unsigned)h << 16) | (unsigned)l;
}
__device__ __forceinline__ float unpackf(unsigned p) {
    return __uint_as_float(p & 0xFFFF0000u) + __uint_as_float(p << 16);
}

// ---------------------------------------------------------------- init ----
__global__ void zero_init_kernel(int* __restrict__ cnt, float* __restrict__ bnacc) {
    int i = blockIdx.x * blockDim.x + threadIdx.x;
    if (i < NN) cnt[i] = 0;
    if (i < 512) bnacc[i] = 0.0f;
}

// ---- range-partitioned histogram: block b handles dst in [r*RSZ,(r+1)*RSZ),
// r = b%RNG (lands on XCD r under round-robin dispatch -> L2-local atomics).
__global__ void hist_ranged_kernel(const int* __restrict__ dst, int* __restrict__ cnt) {
    const int r = blockIdx.x & (RNG - 1);
    const int s = blockIdx.x >> 3;
    const unsigned lo = r * RSZ;
    const int e0 = s * ECH;
    const int e1 = min(e0 + ECH, NE);
    for (int e = e0 + threadIdx.x; e < e1; e += 256) {
        int d = dst[e];
        if ((unsigned)(d - lo) < (unsigned)RSZ) atomicAdd(&cnt[d], 1);
    }
}

// ---- hierarchical scan ----
__global__ void bsum_kernel(const int* __restrict__ cnt, int* __restrict__ bsum) {
    __shared__ int s[256];
    int i = blockIdx.x * 256 + threadIdx.x;
    s[threadIdx.x] = (i < NN) ? cnt[i] : 0;
    __syncthreads();
#pragma unroll
    for (int off = 128; off > 0; off >>= 1) {
        if (threadIdx.x < off) s[threadIdx.x] += s[threadIdx.x + off];
        __syncthreads();
    }
    if (threadIdx.x == 0) bsum[blockIdx.x] = s[0];
}

__global__ void scan_bsum_kernel(int* __restrict__ bsum) {
    __shared__ int s[512];
    int t = threadIdx.x;
    int v = (t < SCAN_G) ? bsum[t] : 0;
    s[t] = v;
    __syncthreads();
    for (int off = 1; off < 512; off <<= 1) {
        int u = (t >= off) ? s[t - off] : 0;
        __syncthreads();
        s[t] += u;
        __syncthreads();
    }
    if (t < SCAN_G) bsum[t] = s[t] - v;   // exclusive
}

__global__ void scan_local_kernel(int* __restrict__ cnt_cursor, const int* __restrict__ bofs,
                                  int* __restrict__ row_start, float* __restrict__ deg_inv) {
    __shared__ int s[256];
    int i = blockIdx.x * 256 + threadIdx.x;
    int c = (i < NN) ? cnt_cursor[i] : 0;
    s[threadIdx.x] = c;
    __syncthreads();
    for (int off = 1; off < 256; off <<= 1) {
        int v = (threadIdx.x >= off) ? s[threadIdx.x - off] : 0;
        __syncthreads();
        s[threadIdx.x] += v;
        __syncthreads();
    }
    int excl = s[threadIdx.x] - c + bofs[blockIdx.x];
    if (i < NN) {
        row_start[i] = excl;
        cnt_cursor[i] = excl;
        deg_inv[i] = 1.0f / (float)(c > 1 ? c : 1);
    }
    if (i == 0) row_start[NN] = NE;
}

// ---- range-partitioned scatter: writes confined to an 800 KB sorted[] window
// per range -> lines fill inside one XCD's L2 instead of 16x write amplification.
__global__ void scatter_ranged_kernel(const int* __restrict__ src, const int* __restrict__ dst,
                                      int* __restrict__ cursor, int* __restrict__ sorted_src) {
    const int r = blockIdx.x & (RNG - 1);
    const int s = blockIdx.x >> 3;
    const unsigned lo = r * RSZ;
    const int e0 = s * ECH;
    const int e1 = min(e0 + ECH, NE);
    for (int e = e0 + threadIdx.x; e < e1; e += 256) {
        int d = dst[e];
        int sv = src[e];
        if ((unsigned)(d - lo) < (unsigned)RSZ) {
            int p = atomicAdd(&cursor[d], 1);
            sorted_src[p] = sv;
        }
    }
}

// ---------------------------------------------------------- converters ----
__global__ void pack_kernel(const float* __restrict__ X, unsigned* __restrict__ P, int n4) {
    int i = blockIdx.x * 256 + threadIdx.x;
    if (i >= n4) return;
    float4 v = ((const float4*)X)[i];
    uint4 o;
    o.x = packf(v.x); o.y = packf(v.y); o.z = packf(v.z); o.w = packf(v.w);
    ((uint4*)P)[i] = o;
}

__global__ void wconv_kernel(const float* w0, const float* w1, const float* w2,
                             const float* w3, const float* w4, const float* w5,
                             const float* w6, const float* w7, const float* w8,
                             const float* w9, const float* w10, unsigned* __restrict__ P) {
    int i = blockIdx.x * 256 + threadIdx.x;  // float4 index
    if (i >= 43008) return;                  // 10*4096 + 2048
    int seg = i >> 12;
    const float* srcs[11] = {w0, w1, w2, w3, w4, w5, w6, w7, w8, w9, w10};
    const float* s = srcs[seg];
    int off = i - (seg << 12);
    float4 v = ((const float4*)s)[off];
    uint4 o;
    o.x = packf(v.x); o.y = packf(v.y); o.z = packf(v.z); o.w = packf(v.w);
    ((uint4*)P)[i] = o;
}

// ------------------------------------------------------------ aggregate ----
template <bool PACKED>
__global__ void aggregate_kernel(const float* __restrict__ Xf, const unsigned* __restrict__ Xp,
                                 const int* __restrict__ row_start,
                                 const int* __restrict__ sorted_src,
                                 const float* __restrict__ deg_inv, unsigned* __restrict__ Mp) {
    int node = blockIdx.x * 8 + (threadIdx.x >> 5);
    int lane = threadIdx.x & 31;
    if (node >= NN) return;
    int e0 = row_start[node];
    int e1 = row_start[node + 1];
    float4 acc = {0.0f, 0.0f, 0.0f, 0.0f};
    for (int e = e0; e < e1; e++) {
        int sn = sorted_src[e];
        if (PACKED) {
            uint4 u = *(const uint4*)&Xp[(size_t)sn * KD + lane * 4];
            acc.x += unpackf(u.x); acc.y += unpackf(u.y);
            acc.z += unpackf(u.z); acc.w += unpackf(u.w);
        } else {
            float4 v = *(const float4*)&Xf[(size_t)sn * KD + lane * 4];
            acc.x += v.x; acc.y += v.y; acc.z += v.z; acc.w += v.w;
        }
    }
    float di = deg_inv[node];
    uint4 o;
    o.x = packf(acc.x * di); o.y = packf(acc.y * di);
    o.z = packf(acc.z * di); o.w = packf(acc.w * di);
    *(uint4*)&Mp[(size_t)node * KD + lane * 4] = o;
}

// ----------------------------------------------------- MFMA split GEMM ----
template <int NOUT, bool RELU, bool DUAL, bool HILO>
__global__ __launch_bounds__(256, 2) void mgemm_kernel(
    const unsigned* __restrict__ A1, const unsigned* __restrict__ W1,
    const unsigned* __restrict__ A2, const unsigned* __restrict__ W2,
    const float* __restrict__ bias, float* __restrict__ Cf, unsigned* __restrict__ Cp) {
    constexpr int LDA = 40;                       // 32 + 8 pad: 2-way max bank aliasing
    __shared__ __align__(16) unsigned short Ash[128 * LDA];
    __shared__ __align__(16) unsigned short Asl[128 * LDA];
    __shared__ __align__(16) unsigned short Wsh[NOUT * LDA];
    __shared__ __align__(16) unsigned short Wsl[NOUT * LDA];

    const int t = threadIdx.x;
    const int i0 = blockIdx.x * 128;
    const int arow = t >> 1;
    const int akp = (t & 1) * 16;
    const int wrow = (NOUT == 128) ? (t >> 1) : (t >> 2);
    const int wkp = (NOUT == 128) ? (t & 1) * 16 : (t & 3) * 8;
    constexpr int WLOAD = (NOUT == 128) ? 16 : 8;

    const int w = t >> 6, lane = t & 63, quad = lane >> 4, mm = lane & 15;
    constexpr int MT = (NOUT == 128) ? 4 : 2;
    constexpr int NT = 4;
    const int rowb = (NOUT == 128) ? (w >> 1) * 64 : w * 32;
    const int colb = (NOUT == 128) ? (w & 1) * 64 : 0;

    f32x4 acc[MT][NT] = {};

    constexpr int STEPS = DUAL ? 8 : 4;
    for (int s = 0; s < STEPS; s++) {
        const unsigned* Ap = (!DUAL || s < 4) ? A1 : A2;
        const unsigned* Wp = (!DUAL || s < 4) ? W1 : W2;
        const int k0 = (s & 3) * 32;
        {   // stage A tile: split packed into hi/lo planes
            int gi = i0 + arow;
            uint4 u[4] = {{0,0,0,0},{0,0,0,0},{0,0,0,0},{0,0,0,0}};
            if (gi < NN) {
                const unsigned* p = Ap + (size_t)gi * KD + k0 + akp;
#pragma unroll
                for (int m = 0; m < 4; m++) u[m] = *(const uint4*)(p + m * 4);
            }
#pragma unroll
            for (int m = 0; m < 4; m++) {
                unsigned* dh = (unsigned*)&Ash[arow * LDA + akp + m * 4];
                unsigned* dl = (unsigned*)&Asl[arow * LDA + akp + m * 4];
                dh[0] = (u[m].x >> 16) | (u[m].y & 0xFFFF0000u);
                dh[1] = (u[m].z >> 16) | (u[m].w & 0xFFFF0000u);
                dl[0] = (u[m].x & 0xFFFFu) | (u[m].y << 16);
                dl[1] = (u[m].z & 0xFFFFu) | (u[m].w << 16);
            }
        }
        {   // stage W tile
            const unsigned* p = Wp + (size_t)wrow * KD + k0 + wkp;
            uint4 u[WLOAD / 4];
#pragma unroll
            for (int m = 0; m < WLOAD / 4; m++) u[m] = *(const uint4*)(p + m * 4);
#pragma unroll
            for (int m = 0; m < WLOAD / 4; m++) {
                unsigned* dh = (unsigned*)&Wsh[wrow * LDA + wkp + m * 4];
                unsigned* dl = (unsigned*)&Wsl[wrow * LDA + wkp + m * 4];
                dh[0] = (u[m].x >> 16) | (u[m].y & 0xFFFF0000u);
                dh[1] = (u[m].z >> 16) | (u[m].w & 0xFFFF0000u);
                dl[0] = (u[m].x & 0xFFFFu) | (u[m].y << 16);
                dl[1] = (u[m].z & 0xFFFFu) | (u[m].w << 16);
            }
        }
        __syncthreads();
        bf16x8 ah[MT], al[MT];
#pragma unroll
        for (int mt = 0; mt < MT; mt++) {
            int off = (rowb + mt * 16 + mm) * LDA + quad * 8;
            ah[mt] = *(const bf16x8*)&Ash[off];
            al[mt] = *(const bf16x8*)&Asl[off];
        }
#pragma unroll
        for (int ng = 0; ng < NT; ng += 2) {
            bf16x8 bh[2], bl[2];
#pragma unroll
            for (int j = 0; j < 2; j++) {
                int off = (colb + (ng + j) * 16 + mm) * LDA + quad * 8;
                bh[j] = *(const bf16x8*)&Wsh[off];
                bl[j] = *(const bf16x8*)&Wsl[off];
            }
#pragma unroll
            for (int mt = 0; mt < MT; mt++)
#pragma unroll
                for (int j = 0; j < 2; j++) {
                    acc[mt][ng + j] = __builtin_amdgcn_mfma_f32_16x16x32_bf16(
                        ah[mt], bh[j], acc[mt][ng + j], 0, 0, 0);
                    acc[mt][ng + j] = __builtin_amdgcn_mfma_f32_16x16x32_bf16(
                        ah[mt], bl[j], acc[mt][ng + j], 0, 0, 0);
                    acc[mt][ng + j] = __builtin_amdgcn_mfma_f32_16x16x32_bf16(
                        al[mt], bh[j], acc[mt][ng + j], 0, 0, 0);
                }
        }
        __syncthreads();
    }
    // epilogue: C/D layout col=lane&15, row=quad*4+reg
#pragma unroll
    for (int mt = 0; mt < MT; mt++)
#pragma unroll
        for (int nt = 0; nt < NT; nt++) {
            int col = colb + nt * 16 + mm;
            float bv = bias[col];
#pragma unroll
            for (int r = 0; r < 4; r++) {
                int row = i0 + rowb + mt * 16 + quad * 4 + r;
                if (row < NN) {
                    float v = acc[mt][nt][r] + bv;
                    if (RELU) v = fmaxf(v, 0.0f);
                    if (HILO) Cp[(size_t)row * NOUT + col] = packf(v);
                    else      Cf[(size_t)row * NOUT + col] = v;
                }
            }
        }
}

// ------------------------------------------------------------------ BN ----
__global__ void bnstats_kernel(const float* __restrict__ Y, float* __restrict__ acc) {
    int col = threadIdx.x & 127;
    int half = threadIdx.x >> 7;
    float s = 0.0f, q = 0.0f;
    for (int i = blockIdx.x * 2 + half; i < NN; i += gridDim.x * 2) {
        float v = Y[(size_t)i * KD + col];
        s += v;
        q += v * v;
    }
    __shared__ float ls[2][128], lq[2][128];
    ls[half][col] = s;
    lq[half][col] = q;
    __syncthreads();
    if (half == 0) {
        s += ls[1][col];
        q += lq[1][col];
        atomicAdd(&acc[col], s);
        atomicAdd(&acc[128 + col], q);
    }
}

__global__ void bnfinal_kernel(const float* __restrict__ acc, const float* __restrict__ g,
                               const float* __restrict__ b, float* __restrict__ scsh) {
    int c = threadIdx.x;
    float mean = acc[c] * (1.0f / NN);
    float var = acc[128 + c] * (1.0f / NN) - mean * mean;
    float sc = g[c] * rsqrtf(var + EPSF);
    scsh[c] = sc;
    scsh[128 + c] = b[c] - mean * sc;
}

// out_packed = pack( relu(Y*scale + shift) + R )
__global__ void bnrelures_kernel(const float* __restrict__ Y, const float* __restrict__ R,
                                 const float* __restrict__ scsh, unsigned* __restrict__ Op) {
    int idx = blockIdx.x * blockDim.x + threadIdx.x;
    const int total = NN * KD / 4;
    if (idx >= total) return;
    int cg = idx & 31;
    float4 y = ((const float4*)Y)[idx];
    float4 r = ((const float4*)R)[idx];
    float4 sc = ((const float4*)scsh)[cg];
    float4 sh = ((const float4*)scsh)[32 + cg];
    uint4 o;
    o.x = packf(fmaxf(y.x * sc.x + sh.x, 0.0f) + r.x);
    o.y = packf(fmaxf(y.y * sc.y + sh.y, 0.0f) + r.y);
    o.z = packf(fmaxf(y.z * sc.z + sh.z, 0.0f) + r.z);
    o.w = packf(fmaxf(y.w * sc.w + sh.w, 0.0f) + r.w);
    ((uint4*)Op)[idx] = o;
}

// --------------------------------------------------------------- launch ----
extern "C" void kernel_launch(void* const* d_in, const int* in_sizes, int n_in,
                              void* d_out, int out_size, void* d_ws, size_t ws_size,
                              hipStream_t stream) {
    const float* x      = (const float*)d_in[0];
    const int*   ei     = (const int*)d_in[1];
    const int*   e_src  = ei;
    const int*   e_dst  = ei + NE;
    const float* s1_wl  = (const float*)d_in[2];
    const float* s1_wr  = (const float*)d_in[3];
    const float* s1_b   = (const float*)d_in[4];
    const float* s2_wl  = (const float*)d_in[5];
    const float* s2_wr  = (const float*)d_in[6];
    const float* s2_b   = (const float*)d_in[7];
    const float* s3_wl  = (const float*)d_in[8];
    const float* s3_wr  = (const float*)d_in[9];
    const float* s3_b   = (const float*)d_in[10];
    const float* bn1_g  = (const float*)d_in[11];
    const float* bn1_b  = (const float*)d_in[12];
    const float* bn2_g  = (const float*)d_in[13];
    const float* bn2_b  = (const float*)d_in[14];
    const float* res1_w = (const float*)d_in[15];
    const float* res1_b = (const float*)d_in[16];
    const float* res2_w = (const float*)d_in[17];
    const float* res2_b = (const float*)d_in[18];
    const float* ff1_w  = (const float*)d_in[19];
    const float* ff1_b  = (const float*)d_in[20];
    const float* ff2_w  = (const float*)d_in[21];
    const float* ff2_b  = (const float*)d_in[22];
    const float* clf_w  = (const float*)d_in[23];
    const float* clf_b  = (const float*)d_in[24];
    float* out = (float*)d_out;

    // workspace carve-up (256B aligned); peak ~214 MB
    char* w = (char*)d_ws;
    auto alloc = [&](size_t bytes) { char* p = w; w += (bytes + 255) & ~(size_t)255; return p; };
    float*    B0        = (float*)alloc((size_t)NN * KD * 4);     // fp32 sage-out
    float*    B1        = (float*)alloc((size_t)NN * KD * 4);     // fp32 residual
    unsigned* P0        = (unsigned*)alloc((size_t)NN * KD * 4);  // packed hi/lo
    unsigned* P1        = (unsigned*)alloc((size_t)NN * KD * 4);  // packed hi/lo
    int*      row_start = (int*)alloc((NN + 1) * 4);
    int*      cursor    = (int*)alloc(NN * 4);
    int*      sorted    = (int*)alloc((size_t)NE * 4);
    float*    deg_inv   = (float*)alloc(NN * 4);
    float*    bnacc     = (float*)alloc(512 * 4);
    float*    bnscsh    = (float*)alloc(512 * 4);
    int*      bsum      = (int*)alloc(SCAN_G * 4);
    unsigned* Wpk       = (unsigned*)alloc(172032 * 4);           // 11 packed weights

    const int GN = (NN + 255) / 256;
    const int GG = (NN + 127) / 128;
    const int GA = (NN + 7) / 8;
    const int GV = (NN * KD / 4 + 255) / 256;
    const int GR = RNG * BPR;                      // ranged CSR-build blocks

    // ---- CSR build (range-partitioned for XCD-local atomics/writes) ----
    zero_init_kernel<<<GN, 256, 0, stream>>>(cursor, bnacc);
    hist_ranged_kernel<<<GR, 256, 0, stream>>>(e_dst, cursor);
    bsum_kernel<<<SCAN_G, 256, 0, stream>>>(cursor, bsum);
    scan_bsum_kernel<<<1, 512, 0, stream>>>(bsum);
    scan_local_kernel<<<SCAN_G, 256, 0, stream>>>(cursor, bsum, row_start, deg_inv);
    scatter_ranged_kernel<<<GR, 256, 0, stream>>>(e_src, e_dst, cursor, sorted);

    // ---- conversions ----
    pack_kernel<<<(NN * KD / 4 + 255) / 256, 256, 0, stream>>>(x, P0, NN * KD / 4); // x -> P0
    wconv_kernel<<<(43008 + 255) / 256, 256, 0, stream>>>(
        res1_w, s1_wl, s1_wr, res2_w, s2_wl, s2_wr, s3_wl, s3_wr, ff1_w, ff2_w, clf_w, Wpk);

    // ---- block 1 ----
    aggregate_kernel<false><<<GA, 256, 0, stream>>>(x, nullptr, row_start, sorted, deg_inv, P1); // mean1
    mgemm_kernel<128, false, false, false><<<GG, 256, 0, stream>>>(
        P0, Wpk + 0 * 16384, nullptr, nullptr, res1_b, B1, nullptr);                 // res1
    mgemm_kernel<128, false, true, false><<<GG, 256, 0, stream>>>(
        P1, Wpk + 1 * 16384, P0, Wpk + 2 * 16384, s1_b, B0, nullptr);                // sage1
    bnstats_kernel<<<512, 256, 0, stream>>>(B0, bnacc);
    bnfinal_kernel<<<1, 128, 0, stream>>>(bnacc, bn1_g, bn1_b, bnscsh);
    bnrelures_kernel<<<GV, 256, 0, stream>>>(B0, B1, bnscsh, P0);                    // h1 -> P0

    // ---- block 2 ----
    aggregate_kernel<true><<<GA, 256, 0, stream>>>(nullptr, P0, row_start, sorted, deg_inv, P1); // mean2
    mgemm_kernel<128, false, false, false><<<GG, 256, 0, stream>>>(
        P0, Wpk + 3 * 16384, nullptr, nullptr, res2_b, B1, nullptr);                 // res2
    mgemm_kernel<128, false, true, false><<<GG, 256, 0, stream>>>(
        P1, Wpk + 4 * 16384, P0, Wpk + 5 * 16384, s2_b, B0, nullptr);                // sage2
    bnstats_kernel<<<512, 256, 0, stream>>>(B0, bnacc + 256);
    bnfinal_kernel<<<1, 128, 0, stream>>>(bnacc + 256, bn2_g, bn2_b, bnscsh + 256);
    bnrelures_kernel<<<GV, 256, 0, stream>>>(B0, B1, bnscsh + 256, P0);              // h2 -> P0

    // ---- block 3 + head ----
    aggregate_kernel<true><<<GA, 256, 0, stream>>>(nullptr, P0, row_start, sorted, deg_inv, P1); // mean3
    mgemm_kernel<128, false, true, true><<<GG, 256, 0, stream>>>(
        P1, Wpk + 6 * 16384, P0, Wpk + 7 * 16384, s3_b, nullptr, P0);                // sage3 -> P0 (in-place safe)
    mgemm_kernel<128, true, false, true><<<GG, 256, 0, stream>>>(
        P0, Wpk + 8 * 16384, nullptr, nullptr, ff1_b, nullptr, P1);                  // ff1+relu -> P1
    mgemm_kernel<128, false, false, true><<<GG, 256, 0, stream>>>(
        P1, Wpk + 9 * 16384, nullptr, nullptr, ff2_b, nullptr, P0);                  // ff2 -> P0
    mgemm_kernel<64, false, false, false><<<GG, 256, 0, stream>>>(
        P0, Wpk + 10 * 16384, nullptr, nullptr, clf_b, out, nullptr);                // clf -> out
}

// Round 6
// 1030.100 us; speedup vs baseline: 1.6718x; 1.0178x over previous
//
#include <hip/hip_runtime.h>

#define NN 100000
#define NE 1600000
#define KD 128
#define EPSF 1e-5f
#define SCAN_G ((NN + 255) / 256)   // 391 scan blocks
#define RNG 8                       // dst-range partitions (≈1 per XCD)
#define BPR 784                     // blocks per range
#define ECH ((NE + BPR - 1) / BPR)  // edges per block slice (2041)
#define RSZ (NN / RNG)              // 12500 nodes per range

typedef __attribute__((ext_vector_type(8))) short bf16x8;
typedef __attribute__((ext_vector_type(4))) float f32x4;

// ---- bf16 split helpers (RNE) ----
__device__ __forceinline__ unsigned short f2bf(float f) {
    unsigned u = __float_as_uint(f);
    u += 0x7FFFu + ((u >> 16) & 1u);
    return (unsigned short)(u >> 16);
}
__device__ __forceinline__ float bfh2f(unsigned short h) {
    return __uint_as_float(((unsigned)h) << 16);
}
// packed fp32 ~= hi + lo, stored as (hi<<16)|lo
__device__ __forceinline__ unsigned packf(float f) {
    unsigned short h = f2bf(f);
    float lo = f - bfh2f(h);
    unsigned short l = f2bf(lo);
    return ((unsigned)h << 16) | (unsigned)l;
}
__device__ __forceinline__ float unpackf(unsigned p) {
    return __uint_as_float(p & 0xFFFF0000u) + __uint_as_float(p << 16);
}

// ---------------------------------------------------------------- init ----
__global__ void zero_init_kernel(int* __restrict__ cnt, float* __restrict__ bnacc) {
    int i = blockIdx.x * blockDim.x + threadIdx.x;
    if (i < NN) cnt[i] = 0;
    if (i < 512) bnacc[i] = 0.0f;
}

// ---- range-partitioned histogram: block b handles dst in [r*RSZ,(r+1)*RSZ) ----
__global__ void hist_ranged_kernel(const int* __restrict__ dst, int* __restrict__ cnt) {
    const int r = blockIdx.x & (RNG - 1);
    const int s = blockIdx.x >> 3;
    const unsigned lo = r * RSZ;
    const int e0 = s * ECH;
    const int e1 = min(e0 + ECH, NE);
    for (int e = e0 + threadIdx.x; e < e1; e += 256) {
        int d = dst[e];
        if ((unsigned)(d - lo) < (unsigned)RSZ) atomicAdd(&cnt[d], 1);
    }
}

// ---- hierarchical scan ----
__global__ void bsum_kernel(const int* __restrict__ cnt, int* __restrict__ bsum) {
    __shared__ int s[256];
    int i = blockIdx.x * 256 + threadIdx.x;
    s[threadIdx.x] = (i < NN) ? cnt[i] : 0;
    __syncthreads();
#pragma unroll
    for (int off = 128; off > 0; off >>= 1) {
        if (threadIdx.x < off) s[threadIdx.x] += s[threadIdx.x + off];
        __syncthreads();
    }
    if (threadIdx.x == 0) bsum[blockIdx.x] = s[0];
}

__global__ void scan_bsum_kernel(int* __restrict__ bsum) {
    __shared__ int s[512];
    int t = threadIdx.x;
    int v = (t < SCAN_G) ? bsum[t] : 0;
    s[t] = v;
    __syncthreads();
    for (int off = 1; off < 512; off <<= 1) {
        int u = (t >= off) ? s[t - off] : 0;
        __syncthreads();
        s[t] += u;
        __syncthreads();
    }
    if (t < SCAN_G) bsum[t] = s[t] - v;   // exclusive
}

__global__ void scan_local_kernel(int* __restrict__ cnt_cursor, const int* __restrict__ bofs,
                                  int* __restrict__ row_start, float* __restrict__ deg_inv) {
    __shared__ int s[256];
    int i = blockIdx.x * 256 + threadIdx.x;
    int c = (i < NN) ? cnt_cursor[i] : 0;
    s[threadIdx.x] = c;
    __syncthreads();
    for (int off = 1; off < 256; off <<= 1) {
        int v = (threadIdx.x >= off) ? s[threadIdx.x - off] : 0;
        __syncthreads();
        s[threadIdx.x] += v;
        __syncthreads();
    }
    int excl = s[threadIdx.x] - c + bofs[blockIdx.x];
    if (i < NN) {
        row_start[i] = excl;
        cnt_cursor[i] = excl;
        deg_inv[i] = 1.0f / (float)(c > 1 ? c : 1);
    }
    if (i == 0) row_start[NN] = NE;
}

// ---- range-partitioned scatter ----
__global__ void scatter_ranged_kernel(const int* __restrict__ src, const int* __restrict__ dst,
                                      int* __restrict__ cursor, int* __restrict__ sorted_src) {
    const int r = blockIdx.x & (RNG - 1);
    const int s = blockIdx.x >> 3;
    const unsigned lo = r * RSZ;
    const int e0 = s * ECH;
    const int e1 = min(e0 + ECH, NE);
    for (int e = e0 + threadIdx.x; e < e1; e += 256) {
        int d = dst[e];
        int sv = src[e];
        if ((unsigned)(d - lo) < (unsigned)RSZ) {
            int p = atomicAdd(&cursor[d], 1);
            sorted_src[p] = sv;
        }
    }
}

// ---------------------------------------------------------- converters ----
__global__ void pack_kernel(const float* __restrict__ X, unsigned* __restrict__ P, int n4) {
    int i = blockIdx.x * 256 + threadIdx.x;
    if (i >= n4) return;
    float4 v = ((const float4*)X)[i];
    uint4 o;
    o.x = packf(v.x); o.y = packf(v.y); o.z = packf(v.z); o.w = packf(v.w);
    ((uint4*)P)[i] = o;
}

__global__ void wconv_kernel(const float* w0, const float* w1, const float* w2,
                             const float* w3, const float* w4, const float* w5,
                             const float* w6, const float* w7, const float* w8,
                             const float* w9, const float* w10, unsigned* __restrict__ P) {
    int i = blockIdx.x * 256 + threadIdx.x;  // float4 index
    if (i >= 43008) return;                  // 10*4096 + 2048
    int seg = i >> 12;
    const float* srcs[11] = {w0, w1, w2, w3, w4, w5, w6, w7, w8, w9, w10};
    const float* s = srcs[seg];
    int off = i - (seg << 12);
    float4 v = ((const float4*)s)[off];
    uint4 o;
    o.x = packf(v.x); o.y = packf(v.y); o.z = packf(v.z); o.w = packf(v.w);
    ((uint4*)P)[i] = o;
}

// ------------------------------------------------------------ aggregate ----
// mean over in-neighbors. 8 nodes/block, 32 lanes x float4. Edge loop
// unrolled x4 with independent accumulators: 4 gathers in flight per lane
// (R5: VGPR=12 -> single outstanding load, latency-bound at 10.7 B/cyc/CU).
template <bool PACKED>
__global__ void aggregate_kernel(const float* __restrict__ Xf, const unsigned* __restrict__ Xp,
                                 const int* __restrict__ row_start,
                                 const int* __restrict__ sorted_src,
                                 const float* __restrict__ deg_inv, unsigned* __restrict__ Mp) {
    int node = blockIdx.x * 8 + (threadIdx.x >> 5);
    int lane = threadIdx.x & 31;
    if (node >= NN) return;
    int e0 = row_start[node];
    int e1 = row_start[node + 1];
    float4 a0 = {0, 0, 0, 0}, a1 = {0, 0, 0, 0}, a2 = {0, 0, 0, 0}, a3 = {0, 0, 0, 0};
    int e = e0;
    for (; e + 4 <= e1; e += 4) {
        int s0 = sorted_src[e + 0];
        int s1 = sorted_src[e + 1];
        int s2 = sorted_src[e + 2];
        int s3 = sorted_src[e + 3];
        if (PACKED) {
            uint4 u0 = *(const uint4*)&Xp[(size_t)s0 * KD + lane * 4];
            uint4 u1 = *(const uint4*)&Xp[(size_t)s1 * KD + lane * 4];
            uint4 u2 = *(const uint4*)&Xp[(size_t)s2 * KD + lane * 4];
            uint4 u3 = *(const uint4*)&Xp[(size_t)s3 * KD + lane * 4];
            a0.x += unpackf(u0.x); a0.y += unpackf(u0.y); a0.z += unpackf(u0.z); a0.w += unpackf(u0.w);
            a1.x += unpackf(u1.x); a1.y += unpackf(u1.y); a1.z += unpackf(u1.z); a1.w += unpackf(u1.w);
            a2.x += unpackf(u2.x); a2.y += unpackf(u2.y); a2.z += unpackf(u2.z); a2.w += unpackf(u2.w);
            a3.x += unpackf(u3.x); a3.y += unpackf(u3.y); a3.z += unpackf(u3.z); a3.w += unpackf(u3.w);
        } else {
            float4 v0 = *(const float4*)&Xf[(size_t)s0 * KD + lane * 4];
            float4 v1 = *(const float4*)&Xf[(size_t)s1 * KD + lane * 4];
            float4 v2 = *(const float4*)&Xf[(size_t)s2 * KD + lane * 4];
            float4 v3 = *(const float4*)&Xf[(size_t)s3 * KD + lane * 4];
            a0.x += v0.x; a0.y += v0.y; a0.z += v0.z; a0.w += v0.w;
            a1.x += v1.x; a1.y += v1.y; a1.z += v1.z; a1.w += v1.w;
            a2.x += v2.x; a2.y += v2.y; a2.z += v2.z; a2.w += v2.w;
            a3.x += v3.x; a3.y += v3.y; a3.z += v3.z; a3.w += v3.w;
        }
    }
    for (; e < e1; e++) {
        int sn = sorted_src[e];
        if (PACKED) {
            uint4 u = *(const uint4*)&Xp[(size_t)sn * KD + lane * 4];
            a0.x += unpackf(u.x); a0.y += unpackf(u.y); a0.z += unpackf(u.z); a0.w += unpackf(u.w);
        } else {
            float4 v = *(const float4*)&Xf[(size_t)sn * KD + lane * 4];
            a0.x += v.x; a0.y += v.y; a0.z += v.z; a0.w += v.w;
        }
    }
    float di = deg_inv[node];
    float4 acc;
    acc.x = ((a0.x + a1.x) + (a2.x + a3.x)) * di;
    acc.y = ((a0.y + a1.y) + (a2.y + a3.y)) * di;
    acc.z = ((a0.z + a1.z) + (a2.z + a3.z)) * di;
    acc.w = ((a0.w + a1.w) + (a2.w + a3.w)) * di;
    uint4 o;
    o.x = packf(acc.x); o.y = packf(acc.y); o.z = packf(acc.z); o.w = packf(acc.w);
    *(uint4*)&Mp[(size_t)node * KD + lane * 4] = o;
}

// ----------------------------------------------------- MFMA split GEMM ----
template <int NOUT, bool RELU, bool DUAL, bool HILO>
__global__ __launch_bounds__(256, 2) void mgemm_kernel(
    const unsigned* __restrict__ A1, const unsigned* __restrict__ W1,
    const unsigned* __restrict__ A2, const unsigned* __restrict__ W2,
    const float* __restrict__ bias, float* __restrict__ Cf, unsigned* __restrict__ Cp) {
    constexpr int LDA = 40;                       // 32 + 8 pad: 2-way max bank aliasing
    __shared__ __align__(16) unsigned short Ash[128 * LDA];
    __shared__ __align__(16) unsigned short Asl[128 * LDA];
    __shared__ __align__(16) unsigned short Wsh[NOUT * LDA];
    __shared__ __align__(16) unsigned short Wsl[NOUT * LDA];

    const int t = threadIdx.x;
    const int i0 = blockIdx.x * 128;
    const int arow = t >> 1;
    const int akp = (t & 1) * 16;
    const int wrow = (NOUT == 128) ? (t >> 1) : (t >> 2);
    const int wkp = (NOUT == 128) ? (t & 1) * 16 : (t & 3) * 8;
    constexpr int WLOAD = (NOUT == 128) ? 16 : 8;

    const int w = t >> 6, lane = t & 63, quad = lane >> 4, mm = lane & 15;
    constexpr int MT = (NOUT == 128) ? 4 : 2;
    constexpr int NT = 4;
    const int rowb = (NOUT == 128) ? (w >> 1) * 64 : w * 32;
    const int colb = (NOUT == 128) ? (w & 1) * 64 : 0;

    f32x4 acc[MT][NT] = {};

    constexpr int STEPS = DUAL ? 8 : 4;
    for (int s = 0; s < STEPS; s++) {
        const unsigned* Ap = (!DUAL || s < 4) ? A1 : A2;
        const unsigned* Wp = (!DUAL || s < 4) ? W1 : W2;
        const int k0 = (s & 3) * 32;
        {   // stage A tile: split packed into hi/lo planes
            int gi = i0 + arow;
            uint4 u[4] = {{0,0,0,0},{0,0,0,0},{0,0,0,0},{0,0,0,0}};
            if (gi < NN) {
                const unsigned* p = Ap + (size_t)gi * KD + k0 + akp;
#pragma unroll
                for (int m = 0; m < 4; m++) u[m] = *(const uint4*)(p + m * 4);
            }
#pragma unroll
            for (int m = 0; m < 4; m++) {
                unsigned* dh = (unsigned*)&Ash[arow * LDA + akp + m * 4];
                unsigned* dl = (unsigned*)&Asl[arow * LDA + akp + m * 4];
                dh[0] = (u[m].x >> 16) | (u[m].y & 0xFFFF0000u);
                dh[1] = (u[m].z >> 16) | (u[m].w & 0xFFFF0000u);
                dl[0] = (u[m].x & 0xFFFFu) | (u[m].y << 16);
                dl[1] = (u[m].z & 0xFFFFu) | (u[m].w << 16);
            }
        }
        {   // stage W tile
            const unsigned* p = Wp + (size_t)wrow * KD + k0 + wkp;
            uint4 u[WLOAD / 4];
#pragma unroll
            for (int m = 0; m < WLOAD / 4; m++) u[m] = *(const uint4*)(p + m * 4);
#pragma unroll
            for (int m = 0; m < WLOAD / 4; m++) {
                unsigned* dh = (unsigned*)&Wsh[wrow * LDA + wkp + m * 4];
                unsigned* dl = (unsigned*)&Wsl[wrow * LDA + wkp + m * 4];
                dh[0] = (u[m].x >> 16) | (u[m].y & 0xFFFF0000u);
                dh[1] = (u[m].z >> 16) | (u[m].w & 0xFFFF0000u);
                dl[0] = (u[m].x & 0xFFFFu) | (u[m].y << 16);
                dl[1] = (u[m].z & 0xFFFFu) | (u[m].w << 16);
            }
        }
        __syncthreads();
        bf16x8 ah[MT], al[MT];
#pragma unroll
        for (int mt = 0; mt < MT; mt++) {
            int off = (rowb + mt * 16 + mm) * LDA + quad * 8;
            ah[mt] = *(const bf16x8*)&Ash[off];
            al[mt] = *(const bf16x8*)&Asl[off];
        }
#pragma unroll
        for (int ng = 0; ng < NT; ng += 2) {
            bf16x8 bh[2], bl[2];
#pragma unroll
            for (int j = 0; j < 2; j++) {
                int off = (colb + (ng + j) * 16 + mm) * LDA + quad * 8;
                bh[j] = *(const bf16x8*)&Wsh[off];
                bl[j] = *(const bf16x8*)&Wsl[off];
            }
#pragma unroll
            for (int mt = 0; mt < MT; mt++)
#pragma unroll
                for (int j = 0; j < 2; j++) {
                    acc[mt][ng + j] = __builtin_amdgcn_mfma_f32_16x16x32_bf16(
                        ah[mt], bh[j], acc[mt][ng + j], 0, 0, 0);
                    acc[mt][ng + j] = __builtin_amdgcn_mfma_f32_16x16x32_bf16(
                        ah[mt], bl[j], acc[mt][ng + j], 0, 0, 0);
                    acc[mt][ng + j] = __builtin_amdgcn_mfma_f32_16x16x32_bf16(
                        al[mt], bh[j], acc[mt][ng + j], 0, 0, 0);
                }
        }
        __syncthreads();
    }
    // epilogue: C/D layout col=lane&15, row=quad*4+reg
#pragma unroll
    for (int mt = 0; mt < MT; mt++)
#pragma unroll
        for (int nt = 0; nt < NT; nt++) {
            int col = colb + nt * 16 + mm;
            float bv = bias[col];
#pragma unroll
            for (int r = 0; r < 4; r++) {
                int row = i0 + rowb + mt * 16 + quad * 4 + r;
                if (row < NN) {
                    float v = acc[mt][nt][r] + bv;
                    if (RELU) v = fmaxf(v, 0.0f);
                    if (HILO) Cp[(size_t)row * NOUT + col] = packf(v);
                    else      Cf[(size_t)row * NOUT + col] = v;
                }
            }
        }
}

// ------------------------------------------------------------------ BN ----
__global__ void bnstats_kernel(const float* __restrict__ Y, float* __restrict__ acc) {
    int col = threadIdx.x & 127;
    int half = threadIdx.x >> 7;
    float s = 0.0f, q = 0.0f;
    for (int i = blockIdx.x * 2 + half; i < NN; i += gridDim.x * 2) {
        float v = Y[(size_t)i * KD + col];
        s += v;
        q += v * v;
    }
    __shared__ float ls[2][128], lq[2][128];
    ls[half][col] = s;
    lq[half][col] = q;
    __syncthreads();
    if (half == 0) {
        s += ls[1][col];
        q += lq[1][col];
        atomicAdd(&acc[col], s);
        atomicAdd(&acc[128 + col], q);
    }
}

__global__ void bnfinal_kernel(const float* __restrict__ acc, const float* __restrict__ g,
                               const float* __restrict__ b, float* __restrict__ scsh) {
    int c = threadIdx.x;
    float mean = acc[c] * (1.0f / NN);
    float var = acc[128 + c] * (1.0f / NN) - mean * mean;
    float sc = g[c] * rsqrtf(var + EPSF);
    scsh[c] = sc;
    scsh[128 + c] = b[c] - mean * sc;
}

// out_packed = pack( relu(Y*scale + shift) + R )
__global__ void bnrelures_kernel(const float* __restrict__ Y, const float* __restrict__ R,
                                 const float* __restrict__ scsh, unsigned* __restrict__ Op) {
    int idx = blockIdx.x * blockDim.x + threadIdx.x;
    const int total = NN * KD / 4;
    if (idx >= total) return;
    int cg = idx & 31;
    float4 y = ((const float4*)Y)[idx];
    float4 r = ((const float4*)R)[idx];
    float4 sc = ((const float4*)scsh)[cg];
    float4 sh = ((const float4*)scsh)[32 + cg];
    uint4 o;
    o.x = packf(fmaxf(y.x * sc.x + sh.x, 0.0f) + r.x);
    o.y = packf(fmaxf(y.y * sc.y + sh.y, 0.0f) + r.y);
    o.z = packf(fmaxf(y.z * sc.z + sh.z, 0.0f) + r.z);
    o.w = packf(fmaxf(y.w * sc.w + sh.w, 0.0f) + r.w);
    ((uint4*)Op)[idx] = o;
}

// --------------------------------------------------------------- launch ----
extern "C" void kernel_launch(void* const* d_in, const int* in_sizes, int n_in,
                              void* d_out, int out_size, void* d_ws, size_t ws_size,
                              hipStream_t stream) {
    const float* x      = (const float*)d_in[0];
    const int*   ei     = (const int*)d_in[1];
    const int*   e_src  = ei;
    const int*   e_dst  = ei + NE;
    const float* s1_wl  = (const float*)d_in[2];
    const float* s1_wr  = (const float*)d_in[3];
    const float* s1_b   = (const float*)d_in[4];
    const float* s2_wl  = (const float*)d_in[5];
    const float* s2_wr  = (const float*)d_in[6];
    const float* s2_b   = (const float*)d_in[7];
    const float* s3_wl  = (const float*)d_in[8];
    const float* s3_wr  = (const float*)d_in[9];
    const float* s3_b   = (const float*)d_in[10];
    const float* bn1_g  = (const float*)d_in[11];
    const float* bn1_b  = (const float*)d_in[12];
    const float* bn2_g  = (const float*)d_in[13];
    const float* bn2_b  = (const float*)d_in[14];
    const float* res1_w = (const float*)d_in[15];
    const float* res1_b = (const float*)d_in[16];
    const float* res2_w = (const float*)d_in[17];
    const float* res2_b = (const float*)d_in[18];
    const float* ff1_w  = (const float*)d_in[19];
    const float* ff1_b  = (const float*)d_in[20];
    const float* ff2_w  = (const float*)d_in[21];
    const float* ff2_b  = (const float*)d_in[22];
    const float* clf_w  = (const float*)d_in[23];
    const float* clf_b  = (const float*)d_in[24];
    float* out = (float*)d_out;

    // workspace carve-up (256B aligned); peak ~214 MB
    char* w = (char*)d_ws;
    auto alloc = [&](size_t bytes) { char* p = w; w += (bytes + 255) & ~(size_t)255; return p; };
    float*    B0        = (float*)alloc((size_t)NN * KD * 4);     // fp32 sage-out
    float*    B1        = (float*)alloc((size_t)NN * KD * 4);     // fp32 residual
    unsigned* P0        = (unsigned*)alloc((size_t)NN * KD * 4);  // packed hi/lo
    unsigned* P1        = (unsigned*)alloc((size_t)NN * KD * 4);  // packed hi/lo
    int*      row_start = (int*)alloc((NN + 1) * 4);
    int*      cursor    = (int*)alloc(NN * 4);
    int*      sorted    = (int*)alloc((size_t)NE * 4);
    float*    deg_inv   = (float*)alloc(NN * 4);
    float*    bnacc     = (float*)alloc(512 * 4);
    float*    bnscsh    = (float*)alloc(512 * 4);
    int*      bsum      = (int*)alloc(SCAN_G * 4);
    unsigned* Wpk       = (unsigned*)alloc(172032 * 4);           // 11 packed weights

    const int GN = (NN + 255) / 256;
    const int GG = (NN + 127) / 128;
    const int GA = (NN + 7) / 8;
    const int GV = (NN * KD / 4 + 255) / 256;
    const int GR = RNG * BPR;                      // ranged CSR-build blocks

    // ---- CSR build (range-partitioned for XCD-local atomics/writes) ----
    zero_init_kernel<<<GN, 256, 0, stream>>>(cursor, bnacc);
    hist_ranged_kernel<<<GR, 256, 0, stream>>>(e_dst, cursor);
    bsum_kernel<<<SCAN_G, 256, 0, stream>>>(cursor, bsum);
    scan_bsum_kernel<<<1, 512, 0, stream>>>(bsum);
    scan_local_kernel<<<SCAN_G, 256, 0, stream>>>(cursor, bsum, row_start, deg_inv);
    scatter_ranged_kernel<<<GR, 256, 0, stream>>>(e_src, e_dst, cursor, sorted);

    // ---- conversions ----
    pack_kernel<<<(NN * KD / 4 + 255) / 256, 256, 0, stream>>>(x, P0, NN * KD / 4); // x -> P0
    wconv_kernel<<<(43008 + 255) / 256, 256, 0, stream>>>(
        res1_w, s1_wl, s1_wr, res2_w, s2_wl, s2_wr, s3_wl, s3_wr, ff1_w, ff2_w, clf_w, Wpk);

    // ---- block 1 ----
    aggregate_kernel<false><<<GA, 256, 0, stream>>>(x, nullptr, row_start, sorted, deg_inv, P1); // mean1
    mgemm_kernel<128, false, false, false><<<GG, 256, 0, stream>>>(
        P0, Wpk + 0 * 16384, nullptr, nullptr, res1_b, B1, nullptr);                 // res1
    mgemm_kernel<128, false, true, false><<<GG, 256, 0, stream>>>(
        P1, Wpk + 1 * 16384, P0, Wpk + 2 * 16384, s1_b, B0, nullptr);                // sage1
    bnstats_kernel<<<512, 256, 0, stream>>>(B0, bnacc);
    bnfinal_kernel<<<1, 128, 0, stream>>>(bnacc, bn1_g, bn1_b, bnscsh);
    bnrelures_kernel<<<GV, 256, 0, stream>>>(B0, B1, bnscsh, P0);                    // h1 -> P0

    // ---- block 2 ----
    aggregate_kernel<true><<<GA, 256, 0, stream>>>(nullptr, P0, row_start, sorted, deg_inv, P1); // mean2
    mgemm_kernel<128, false, false, false><<<GG, 256, 0, stream>>>(
        P0, Wpk + 3 * 16384, nullptr, nullptr, res2_b, B1, nullptr);                 // res2
    mgemm_kernel<128, false, true, false><<<GG, 256, 0, stream>>>(
        P1, Wpk + 4 * 16384, P0, Wpk + 5 * 16384, s2_b, B0, nullptr);                // sage2
    bnstats_kernel<<<512, 256, 0, stream>>>(B0, bnacc + 256);
    bnfinal_kernel<<<1, 128, 0, stream>>>(bnacc + 256, bn2_g, bn2_b, bnscsh + 256);
    bnrelures_kernel<<<GV, 256, 0, stream>>>(B0, B1, bnscsh + 256, P0);              // h2 -> P0

    // ---- block 3 + head ----
    aggregate_kernel<true><<<GA, 256, 0, stream>>>(nullptr, P0, row_start, sorted, deg_inv, P1); // mean3
    mgemm_kernel<128, false, true, true><<<GG, 256, 0, stream>>>(
        P1, Wpk + 6 * 16384, P0, Wpk + 7 * 16384, s3_b, nullptr, P0);                // sage3 -> P0 (in-place safe)
    mgemm_kernel<128, true, false, true><<<GG, 256, 0, stream>>>(
        P0, Wpk + 8 * 16384, nullptr, nullptr, ff1_b, nullptr, P1);                  // ff1+relu -> P1
    mgemm_kernel<128, false, false, true><<<GG, 256, 0, stream>>>(
        P1, Wpk + 9 * 16384, nullptr, nullptr, ff2_b, nullptr, P0);                  // ff2 -> P0
    mgemm_kernel<64, false, false, false><<<GG, 256, 0, stream>>>(
        P0, Wpk + 10 * 16384, nullptr, nullptr, clf_b, out, nullptr);                // clf -> out
}

// Round 7
// 1010.009 us; speedup vs baseline: 1.7051x; 1.0199x over previous
//
#include <hip/hip_runtime.h>

#define NN 100000
#define NE 1600000
#define KD 128
#define EPSF 1e-5f
#define SCAN_G ((NN + 255) / 256)   // 391 scan blocks
#define RNG 8                       // dst-range partitions (≈1 per XCD)
#define BPR 784                     // blocks per range
#define ECH ((NE + BPR - 1) / BPR)  // edges per block slice (2041)
#define RSZ (NN / RNG)              // 12500 nodes per range
#define WPLANE 16384                // 128*128 weight plane (ushort elems)

typedef __attribute__((ext_vector_type(8))) short bf16x8;
typedef __attribute__((ext_vector_type(8))) unsigned short ushort8;
typedef __attribute__((ext_vector_type(4))) unsigned short ushort4v;
typedef __attribute__((ext_vector_type(4))) float f32x4;

// ---- bf16 split helpers (RNE) ----
__device__ __forceinline__ unsigned short f2bf(float f) {
    unsigned u = __float_as_uint(f);
    u += 0x7FFFu + ((u >> 16) & 1u);
    return (unsigned short)(u >> 16);
}
__device__ __forceinline__ float bfh2f(unsigned short h) {
    return __uint_as_float(((unsigned)h) << 16);
}
__device__ __forceinline__ unsigned packf(float f) {   // (hi<<16)|lo for gather path
    unsigned short h = f2bf(f);
    float lo = f - bfh2f(h);
    unsigned short l = f2bf(lo);
    return ((unsigned)h << 16) | (unsigned)l;
}
__device__ __forceinline__ float unpackf(unsigned p) {
    return __uint_as_float(p & 0xFFFF0000u) + __uint_as_float(p << 16);
}

// ---------------------------------------------------------------- init ----
__global__ void zero_init_kernel(int* __restrict__ cnt, float* __restrict__ bnacc) {
    int i = blockIdx.x * blockDim.x + threadIdx.x;
    if (i < NN) cnt[i] = 0;
    if (i < 512) bnacc[i] = 0.0f;
}

__global__ void hist_ranged_kernel(const int* __restrict__ dst, int* __restrict__ cnt) {
    const int r = blockIdx.x & (RNG - 1);
    const int s = blockIdx.x >> 3;
    const unsigned lo = r * RSZ;
    const int e0 = s * ECH;
    const int e1 = min(e0 + ECH, NE);
    for (int e = e0 + threadIdx.x; e < e1; e += 256) {
        int d = dst[e];
        if ((unsigned)(d - lo) < (unsigned)RSZ) atomicAdd(&cnt[d], 1);
    }
}

__global__ void bsum_kernel(const int* __restrict__ cnt, int* __restrict__ bsum) {
    __shared__ int s[256];
    int i = blockIdx.x * 256 + threadIdx.x;
    s[threadIdx.x] = (i < NN) ? cnt[i] : 0;
    __syncthreads();
#pragma unroll
    for (int off = 128; off > 0; off >>= 1) {
        if (threadIdx.x < off) s[threadIdx.x] += s[threadIdx.x + off];
        __syncthreads();
    }
    if (threadIdx.x == 0) bsum[blockIdx.x] = s[0];
}

__global__ void scan_bsum_kernel(int* __restrict__ bsum) {
    __shared__ int s[512];
    int t = threadIdx.x;
    int v = (t < SCAN_G) ? bsum[t] : 0;
    s[t] = v;
    __syncthreads();
    for (int off = 1; off < 512; off <<= 1) {
        int u = (t >= off) ? s[t - off] : 0;
        __syncthreads();
        s[t] += u;
        __syncthreads();
    }
    if (t < SCAN_G) bsum[t] = s[t] - v;   // exclusive
}

__global__ void scan_local_kernel(int* __restrict__ cnt_cursor, const int* __restrict__ bofs,
                                  int* __restrict__ row_start, float* __restrict__ deg_inv) {
    __shared__ int s[256];
    int i = blockIdx.x * 256 + threadIdx.x;
    int c = (i < NN) ? cnt_cursor[i] : 0;
    s[threadIdx.x] = c;
    __syncthreads();
    for (int off = 1; off < 256; off <<= 1) {
        int v = (threadIdx.x >= off) ? s[threadIdx.x - off] : 0;
        __syncthreads();
        s[threadIdx.x] += v;
        __syncthreads();
    }
    int excl = s[threadIdx.x] - c + bofs[blockIdx.x];
    if (i < NN) {
        row_start[i] = excl;
        cnt_cursor[i] = excl;
        deg_inv[i] = 1.0f / (float)(c > 1 ? c : 1);
    }
    if (i == 0) row_start[NN] = NE;
}

__global__ void scatter_ranged_kernel(const int* __restrict__ src, const int* __restrict__ dst,
                                      int* __restrict__ cursor, int* __restrict__ sorted_src) {
    const int r = blockIdx.x & (RNG - 1);
    const int s = blockIdx.x >> 3;
    const unsigned lo = r * RSZ;
    const int e0 = s * ECH;
    const int e1 = min(e0 + ECH, NE);
    for (int e = e0 + threadIdx.x; e < e1; e += 256) {
        int d = dst[e];
        int sv = src[e];
        if ((unsigned)(d - lo) < (unsigned)RSZ) {
            int p = atomicAdd(&cursor[d], 1);
            sorted_src[p] = sv;
        }
    }
}

// ---------------------------------------------------------- converters ----
// fp32 -> separate hi/lo bf16 planes
__global__ void pack_planes_kernel(const float* __restrict__ X,
                                   unsigned short* __restrict__ Ph,
                                   unsigned short* __restrict__ Pl, int n4) {
    int i = blockIdx.x * 256 + threadIdx.x;
    if (i >= n4) return;
    float4 v = ((const float4*)X)[i];
    ushort4v h, l;
    h.x = f2bf(v.x); l.x = f2bf(v.x - bfh2f(h.x));
    h.y = f2bf(v.y); l.y = f2bf(v.y - bfh2f(h.y));
    h.z = f2bf(v.z); l.z = f2bf(v.z - bfh2f(h.z));
    h.w = f2bf(v.w); l.w = f2bf(v.w - bfh2f(h.w));
    *(ushort4v*)&Ph[i * 4] = h;
    *(ushort4v*)&Pl[i * 4] = l;
}

// 11 weight matrices -> hi planes at j*WPLANE, lo planes at (11+j)*WPLANE
__global__ void wconv_kernel(const float* w0, const float* w1, const float* w2,
                             const float* w3, const float* w4, const float* w5,
                             const float* w6, const float* w7, const float* w8,
                             const float* w9, const float* w10,
                             unsigned short* __restrict__ P) {
    int i = blockIdx.x * 256 + threadIdx.x;  // float4 index
    if (i >= 43008) return;                  // 10*4096 + 2048
    int seg = i >> 12;
    const float* srcs[11] = {w0, w1, w2, w3, w4, w5, w6, w7, w8, w9, w10};
    const float* s = srcs[seg];
    int off = i - (seg << 12);
    float4 v = ((const float4*)s)[off];
    ushort4v h, l;
    h.x = f2bf(v.x); l.x = f2bf(v.x - bfh2f(h.x));
    h.y = f2bf(v.y); l.y = f2bf(v.y - bfh2f(h.y));
    h.z = f2bf(v.z); l.z = f2bf(v.z - bfh2f(h.z));
    h.w = f2bf(v.w); l.w = f2bf(v.w - bfh2f(h.w));
    *(ushort4v*)&P[(size_t)seg * WPLANE + off * 4] = h;
    *(ushort4v*)&P[(size_t)(11 + seg) * WPLANE + off * 4] = l;
}

// ------------------------------------------------------------ aggregate ----
// mean over in-neighbors -> hi/lo planes. 8 nodes/block, 32 lanes x float4.
// x4 unroll (R6: hierarchy-BW bound ~7 TB/s delivered; keep best known form).
template <bool PACKED>
__global__ void aggregate_kernel(const float* __restrict__ Xf, const unsigned* __restrict__ Xp,
                                 const int* __restrict__ row_start,
                                 const int* __restrict__ sorted_src,
                                 const float* __restrict__ deg_inv,
                                 unsigned short* __restrict__ Mh,
                                 unsigned short* __restrict__ Ml) {
    int node = blockIdx.x * 8 + (threadIdx.x >> 5);
    int lane = threadIdx.x & 31;
    if (node >= NN) return;
    int e0 = row_start[node];
    int e1 = row_start[node + 1];
    float4 a0 = {0, 0, 0, 0}, a1 = {0, 0, 0, 0}, a2 = {0, 0, 0, 0}, a3 = {0, 0, 0, 0};
    int e = e0;
    for (; e + 4 <= e1; e += 4) {
        int s0 = sorted_src[e + 0];
        int s1 = sorted_src[e + 1];
        int s2 = sorted_src[e + 2];
        int s3 = sorted_src[e + 3];
        if (PACKED) {
            uint4 u0 = *(const uint4*)&Xp[(size_t)s0 * KD + lane * 4];
            uint4 u1 = *(const uint4*)&Xp[(size_t)s1 * KD + lane * 4];
            uint4 u2 = *(const uint4*)&Xp[(size_t)s2 * KD + lane * 4];
            uint4 u3 = *(const uint4*)&Xp[(size_t)s3 * KD + lane * 4];
            a0.x += unpackf(u0.x); a0.y += unpackf(u0.y); a0.z += unpackf(u0.z); a0.w += unpackf(u0.w);
            a1.x += unpackf(u1.x); a1.y += unpackf(u1.y); a1.z += unpackf(u1.z); a1.w += unpackf(u1.w);
            a2.x += unpackf(u2.x); a2.y += unpackf(u2.y); a2.z += unpackf(u2.z); a2.w += unpackf(u2.w);
            a3.x += unpackf(u3.x); a3.y += unpackf(u3.y); a3.z += unpackf(u3.z); a3.w += unpackf(u3.w);
        } else {
            float4 v0 = *(const float4*)&Xf[(size_t)s0 * KD + lane * 4];
            float4 v1 = *(const float4*)&Xf[(size_t)s1 * KD + lane * 4];
            float4 v2 = *(const float4*)&Xf[(size_t)s2 * KD + lane * 4];
            float4 v3 = *(const float4*)&Xf[(size_t)s3 * KD + lane * 4];
            a0.x += v0.x; a0.y += v0.y; a0.z += v0.z; a0.w += v0.w;
            a1.x += v1.x; a1.y += v1.y; a1.z += v1.z; a1.w += v1.w;
            a2.x += v2.x; a2.y += v2.y; a2.z += v2.z; a2.w += v2.w;
            a3.x += v3.x; a3.y += v3.y; a3.z += v3.z; a3.w += v3.w;
        }
    }
    for (; e < e1; e++) {
        int sn = sorted_src[e];
        if (PACKED) {
            uint4 u = *(const uint4*)&Xp[(size_t)sn * KD + lane * 4];
            a0.x += unpackf(u.x); a0.y += unpackf(u.y); a0.z += unpackf(u.z); a0.w += unpackf(u.w);
        } else {
            float4 v = *(const float4*)&Xf[(size_t)sn * KD + lane * 4];
            a0.x += v.x; a0.y += v.y; a0.z += v.z; a0.w += v.w;
        }
    }
    float di = deg_inv[node];
    float4 acc;
    acc.x = ((a0.x + a1.x) + (a2.x + a3.x)) * di;
    acc.y = ((a0.y + a1.y) + (a2.y + a3.y)) * di;
    acc.z = ((a0.z + a1.z) + (a2.z + a3.z)) * di;
    acc.w = ((a0.w + a1.w) + (a2.w + a3.w)) * di;
    ushort4v h, l;
    h.x = f2bf(acc.x); l.x = f2bf(acc.x - bfh2f(h.x));
    h.y = f2bf(acc.y); l.y = f2bf(acc.y - bfh2f(h.y));
    h.z = f2bf(acc.z); l.z = f2bf(acc.z - bfh2f(h.z));
    h.w = f2bf(acc.w); l.w = f2bf(acc.w - bfh2f(h.w));
    *(ushort4v*)&Mh[(size_t)node * KD + lane * 4] = h;
    *(ushort4v*)&Ml[(size_t)node * KD + lane * 4] = l;
}

// ----------------------------------------------------- MFMA split GEMM v2 ----
// C = act( A1@W1^T (+ A2@W2^T) + bias ); operands pre-split hi/lo bf16 planes.
// 64-row x NOUT tile, 256 thr (4 waves), 1563 blocks, LDS ~30 KB.
// Per wave: 64x32 (NOUT=128) via 4x2 tiles of 16x16x32, 3 MFMAs/tile (hi/lo split).
template <int NOUT, bool RELU, bool DUAL, bool HILO>
__global__ __launch_bounds__(256, 3) void mgemm2_kernel(
    const unsigned short* __restrict__ A1h, const unsigned short* __restrict__ A1l,
    const unsigned short* __restrict__ A2h, const unsigned short* __restrict__ A2l,
    const unsigned short* __restrict__ W1h, const unsigned short* __restrict__ W1l,
    const unsigned short* __restrict__ W2h, const unsigned short* __restrict__ W2l,
    const float* __restrict__ bias, float* __restrict__ Cf,
    unsigned short* __restrict__ Chi, unsigned short* __restrict__ Clo) {
    constexpr int LDA = 40;                       // 32 + 8 pad
    __shared__ __align__(16) unsigned short Ash[64 * LDA];
    __shared__ __align__(16) unsigned short Asl[64 * LDA];
    __shared__ __align__(16) unsigned short Wsh[NOUT * LDA];
    __shared__ __align__(16) unsigned short Wsl[NOUT * LDA];

    const int t = threadIdx.x;
    const int i0 = blockIdx.x * 64;
    const int w = t >> 6, lane = t & 63, quad = lane >> 4, mm = lane & 15;
    constexpr int NT = (NOUT == 128) ? 2 : 1;
    const int colb = w * ((NOUT == 128) ? 32 : 16);

    // staging maps
    const int arow = t >> 2, akc = (t & 3) * 8;   // 64 rows x 4 chunks
    f32x4 acc[4][NT] = {};

    constexpr int STEPS = DUAL ? 8 : 4;
    for (int s = 0; s < STEPS; s++) {
        const unsigned short* pAh = (!DUAL || s < 4) ? A1h : A2h;
        const unsigned short* pAl = (!DUAL || s < 4) ? A1l : A2l;
        const unsigned short* pWh = (!DUAL || s < 4) ? W1h : W2h;
        const unsigned short* pWl = (!DUAL || s < 4) ? W1l : W2l;
        const int k0 = (s & 3) * 32;
        {   // stage A: 1 chunk per plane per thread
            int gi = min(i0 + arow, NN - 1);
            ushort8 vh = *(const ushort8*)&pAh[(size_t)gi * KD + k0 + akc];
            ushort8 vl = *(const ushort8*)&pAl[(size_t)gi * KD + k0 + akc];
            *(ushort8*)&Ash[arow * LDA + akc] = vh;
            *(ushort8*)&Asl[arow * LDA + akc] = vl;
        }
        if (NOUT == 128) {   // stage W: 2 chunks per plane per thread
#pragma unroll
            for (int hh = 0; hh < 2; hh++) {
                int c = t + hh * 256;
                int wr = c >> 2, wkc = (c & 3) * 8;
                ushort8 vh = *(const ushort8*)&pWh[(size_t)wr * KD + k0 + wkc];
                ushort8 vl = *(const ushort8*)&pWl[(size_t)wr * KD + k0 + wkc];
                *(ushort8*)&Wsh[wr * LDA + wkc] = vh;
                *(ushort8*)&Wsl[wr * LDA + wkc] = vl;
            }
        } else {             // NOUT=64: 1 chunk per plane per thread
            int wr = t >> 2, wkc = (t & 3) * 8;
            ushort8 vh = *(const ushort8*)&pWh[(size_t)wr * KD + k0 + wkc];
            ushort8 vl = *(const ushort8*)&pWl[(size_t)wr * KD + k0 + wkc];
            *(ushort8*)&Wsh[wr * LDA + wkc] = vh;
            *(ushort8*)&Wsl[wr * LDA + wkc] = vl;
        }
        __syncthreads();
        bf16x8 ah[4], al[4];
#pragma unroll
        for (int mt = 0; mt < 4; mt++) {
            int off = (mt * 16 + mm) * LDA + quad * 8;
            ah[mt] = *(const bf16x8*)&Ash[off];
            al[mt] = *(const bf16x8*)&Asl[off];
        }
#pragma unroll
        for (int nt = 0; nt < NT; nt++) {
            int woff = (colb + nt * 16 + mm) * LDA + quad * 8;
            bf16x8 bh = *(const bf16x8*)&Wsh[woff];
            bf16x8 bl = *(const bf16x8*)&Wsl[woff];
#pragma unroll
            for (int mt = 0; mt < 4; mt++) {
                acc[mt][nt] = __builtin_amdgcn_mfma_f32_16x16x32_bf16(ah[mt], bh, acc[mt][nt], 0, 0, 0);
                acc[mt][nt] = __builtin_amdgcn_mfma_f32_16x16x32_bf16(ah[mt], bl, acc[mt][nt], 0, 0, 0);
                acc[mt][nt] = __builtin_amdgcn_mfma_f32_16x16x32_bf16(al[mt], bh, acc[mt][nt], 0, 0, 0);
            }
        }
        __syncthreads();
    }
    // epilogue: C/D layout col=lane&15, row=quad*4+reg
#pragma unroll
    for (int mt = 0; mt < 4; mt++)
#pragma unroll
        for (int nt = 0; nt < NT; nt++) {
            int col = colb + nt * 16 + mm;
            float bv = bias[col];
#pragma unroll
            for (int r = 0; r < 4; r++) {
                int row = i0 + mt * 16 + quad * 4 + r;
                if (row < NN) {
                    float v = acc[mt][nt][r] + bv;
                    if (RELU) v = fmaxf(v, 0.0f);
                    if (HILO) {
                        unsigned short h = f2bf(v);
                        Chi[(size_t)row * NOUT + col] = h;
                        Clo[(size_t)row * NOUT + col] = f2bf(v - bfh2f(h));
                    } else {
                        Cf[(size_t)row * NOUT + col] = v;
                    }
                }
            }
        }
}

// ------------------------------------------------------------------ BN ----
__global__ void bnstats_kernel(const float* __restrict__ Y, float* __restrict__ acc) {
    int col = threadIdx.x & 127;
    int half = threadIdx.x >> 7;
    float s = 0.0f, q = 0.0f;
    for (int i = blockIdx.x * 2 + half; i < NN; i += gridDim.x * 2) {
        float v = Y[(size_t)i * KD + col];
        s += v;
        q += v * v;
    }
    __shared__ float ls[2][128], lq[2][128];
    ls[half][col] = s;
    lq[half][col] = q;
    __syncthreads();
    if (half == 0) {
        s += ls[1][col];
        q += lq[1][col];
        atomicAdd(&acc[col], s);
        atomicAdd(&acc[128 + col], q);
    }
}

__global__ void bnfinal_kernel(const float* __restrict__ acc, const float* __restrict__ g,
                               const float* __restrict__ b, float* __restrict__ scsh) {
    int c = threadIdx.x;
    float mean = acc[c] * (1.0f / NN);
    float var = acc[128 + c] * (1.0f / NN) - mean * mean;
    float sc = g[c] * rsqrtf(var + EPSF);
    scsh[c] = sc;
    scsh[128 + c] = b[c] - mean * sc;
}

// h = relu(Y*scale+shift)+R  -> packed (for gather) + hi/lo planes (for GEMM)
__global__ void bnrelures_kernel(const float* __restrict__ Y, const float* __restrict__ R,
                                 const float* __restrict__ scsh, unsigned* __restrict__ Op,
                                 unsigned short* __restrict__ Sh, unsigned short* __restrict__ Sl) {
    int idx = blockIdx.x * blockDim.x + threadIdx.x;
    const int total = NN * KD / 4;
    if (idx >= total) return;
    int cg = idx & 31;
    float4 y = ((const float4*)Y)[idx];
    float4 r = ((const float4*)R)[idx];
    float4 sc = ((const float4*)scsh)[cg];
    float4 sh = ((const float4*)scsh)[32 + cg];
    float v0 = fmaxf(y.x * sc.x + sh.x, 0.0f) + r.x;
    float v1 = fmaxf(y.y * sc.y + sh.y, 0.0f) + r.y;
    float v2 = fmaxf(y.z * sc.z + sh.z, 0.0f) + r.z;
    float v3 = fmaxf(y.w * sc.w + sh.w, 0.0f) + r.w;
    ushort4v h, l;
    h.x = f2bf(v0); l.x = f2bf(v0 - bfh2f(h.x));
    h.y = f2bf(v1); l.y = f2bf(v1 - bfh2f(h.y));
    h.z = f2bf(v2); l.z = f2bf(v2 - bfh2f(h.z));
    h.w = f2bf(v3); l.w = f2bf(v3 - bfh2f(h.w));
    uint4 o;
    o.x = ((unsigned)h.x << 16) | l.x;
    o.y = ((unsigned)h.y << 16) | l.y;
    o.z = ((unsigned)h.z << 16) | l.z;
    o.w = ((unsigned)h.w << 16) | l.w;
    ((uint4*)Op)[idx] = o;
    *(ushort4v*)&Sh[idx * 4] = h;
    *(ushort4v*)&Sl[idx * 4] = l;
}

// --------------------------------------------------------------- launch ----
extern "C" void kernel_launch(void* const* d_in, const int* in_sizes, int n_in,
                              void* d_out, int out_size, void* d_ws, size_t ws_size,
                              hipStream_t stream) {
    const float* x      = (const float*)d_in[0];
    const int*   ei     = (const int*)d_in[1];
    const int*   e_src  = ei;
    const int*   e_dst  = ei + NE;
    const float* s1_b   = (const float*)d_in[4];
    const float* s2_b   = (const float*)d_in[7];
    const float* s3_b   = (const float*)d_in[10];
    const float* bn1_g  = (const float*)d_in[11];
    const float* bn1_b  = (const float*)d_in[12];
    const float* bn2_g  = (const float*)d_in[13];
    const float* bn2_b  = (const float*)d_in[14];
    const float* res1_b = (const float*)d_in[16];
    const float* res2_b = (const float*)d_in[18];
    const float* ff1_b  = (const float*)d_in[20];
    const float* ff2_b  = (const float*)d_in[22];
    const float* clf_b  = (const float*)d_in[24];
    float* out = (float*)d_out;

    // workspace carve-up (256B aligned); peak ~290 MB
    char* w = (char*)d_ws;
    auto alloc = [&](size_t bytes) { char* p = w; w += (bytes + 255) & ~(size_t)255; return p; };
    float*          B0   = (float*)alloc((size_t)NN * KD * 4);            // fp32 sage-out
    float*          B1   = (float*)alloc((size_t)NN * KD * 4);            // fp32 residual
    unsigned*       Ppk  = (unsigned*)alloc((size_t)NN * KD * 4);         // packed h (gather)
    unsigned short* S0h  = (unsigned short*)alloc((size_t)NN * KD * 2);   // plane set 0
    unsigned short* S0l  = (unsigned short*)alloc((size_t)NN * KD * 2);
    unsigned short* S1h  = (unsigned short*)alloc((size_t)NN * KD * 2);   // plane set 1
    unsigned short* S1l  = (unsigned short*)alloc((size_t)NN * KD * 2);
    int*   row_start = (int*)alloc((NN + 1) * 4);
    int*   cursor    = (int*)alloc(NN * 4);
    int*   sorted    = (int*)alloc((size_t)NE * 4);
    float* deg_inv   = (float*)alloc(NN * 4);
    float* bnacc     = (float*)alloc(512 * 4);
    float* bnscsh    = (float*)alloc(512 * 4);
    int*   bsum      = (int*)alloc(SCAN_G * 4);
    unsigned short* Wpl = (unsigned short*)alloc((size_t)22 * WPLANE * 2); // 11 hi + 11 lo planes

    auto WH = [&](int j) { return Wpl + (size_t)j * WPLANE; };
    auto WL = [&](int j) { return Wpl + (size_t)(11 + j) * WPLANE; };

    const int GN = (NN + 255) / 256;
    const int GG2 = (NN + 63) / 64;                // 1563 gemm blocks
    const int GA = (NN + 7) / 8;
    const int GV = (NN * KD / 4 + 255) / 256;
    const int GR = RNG * BPR;

    // ---- CSR build (range-partitioned) ----
    zero_init_kernel<<<GN, 256, 0, stream>>>(cursor, bnacc);
    hist_ranged_kernel<<<GR, 256, 0, stream>>>(e_dst, cursor);
    bsum_kernel<<<SCAN_G, 256, 0, stream>>>(cursor, bsum);
    scan_bsum_kernel<<<1, 512, 0, stream>>>(bsum);
    scan_local_kernel<<<SCAN_G, 256, 0, stream>>>(cursor, bsum, row_start, deg_inv);
    scatter_ranged_kernel<<<GR, 256, 0, stream>>>(e_src, e_dst, cursor, sorted);

    // ---- conversions ----
    pack_planes_kernel<<<GV, 256, 0, stream>>>(x, S0h, S0l, NN * KD / 4);   // x -> S0 planes
    wconv_kernel<<<(43008 + 255) / 256, 256, 0, stream>>>(
        (const float*)d_in[15], (const float*)d_in[2], (const float*)d_in[3],   // res1_w, s1_wl, s1_wr
        (const float*)d_in[17], (const float*)d_in[5], (const float*)d_in[6],   // res2_w, s2_wl, s2_wr
        (const float*)d_in[8], (const float*)d_in[9],                            // s3_wl, s3_wr
        (const float*)d_in[19], (const float*)d_in[21], (const float*)d_in[23], // ff1_w, ff2_w, clf_w
        Wpl);

    // ---- block 1 ----
    aggregate_kernel<false><<<GA, 256, 0, stream>>>(x, nullptr, row_start, sorted, deg_inv, S1h, S1l);
    mgemm2_kernel<128, false, false, false><<<GG2, 256, 0, stream>>>(
        S0h, S0l, nullptr, nullptr, WH(0), WL(0), nullptr, nullptr, res1_b, B1, nullptr, nullptr);  // res1
    mgemm2_kernel<128, false, true, false><<<GG2, 256, 0, stream>>>(
        S1h, S1l, S0h, S0l, WH(1), WL(1), WH(2), WL(2), s1_b, B0, nullptr, nullptr);                // sage1
    bnstats_kernel<<<512, 256, 0, stream>>>(B0, bnacc);
    bnfinal_kernel<<<1, 128, 0, stream>>>(bnacc, bn1_g, bn1_b, bnscsh);
    bnrelures_kernel<<<GV, 256, 0, stream>>>(B0, B1, bnscsh, Ppk, S0h, S0l);   // h1 -> Ppk + S0

    // ---- block 2 ----
    aggregate_kernel<true><<<GA, 256, 0, stream>>>(nullptr, Ppk, row_start, sorted, deg_inv, S1h, S1l);
    mgemm2_kernel<128, false, false, false><<<GG2, 256, 0, stream>>>(
        S0h, S0l, nullptr, nullptr, WH(3), WL(3), nullptr, nullptr, res2_b, B1, nullptr, nullptr);  // res2
    mgemm2_kernel<128, false, true, false><<<GG2, 256, 0, stream>>>(
        S1h, S1l, S0h, S0l, WH(4), WL(4), WH(5), WL(5), s2_b, B0, nullptr, nullptr);                // sage2
    bnstats_kernel<<<512, 256, 0, stream>>>(B0, bnacc + 256);
    bnfinal_kernel<<<1, 128, 0, stream>>>(bnacc + 256, bn2_g, bn2_b, bnscsh + 256);
    bnrelures_kernel<<<GV, 256, 0, stream>>>(B0, B1, bnscsh + 256, Ppk, S0h, S0l);  // h2 -> Ppk + S0

    // ---- block 3 + head ----
    aggregate_kernel<true><<<GA, 256, 0, stream>>>(nullptr, Ppk, row_start, sorted, deg_inv, S1h, S1l);
    mgemm2_kernel<128, false, true, true><<<GG2, 256, 0, stream>>>(
        S1h, S1l, S0h, S0l, WH(6), WL(6), WH(7), WL(7), s3_b, nullptr, S0h, S0l);   // sage3 -> S0 (in-place safe: per-block rows)
    mgemm2_kernel<128, true, false, true><<<GG2, 256, 0, stream>>>(
        S0h, S0l, nullptr, nullptr, WH(8), WL(8), nullptr, nullptr, ff1_b, nullptr, S1h, S1l);  // ff1+relu
    mgemm2_kernel<128, false, false, true><<<GG2, 256, 0, stream>>>(
        S1h, S1l, nullptr, nullptr, WH(9), WL(9), nullptr, nullptr, ff2_b, nullptr, S0h, S0l);  // ff2
    mgemm2_kernel<64, false, false, false><<<GG2, 256, 0, stream>>>(
        S0h, S0l, nullptr, nullptr, WH(10), WL(10), nullptr, nullptr, clf_b, out, nullptr, nullptr); // clf
}